// Round 19
// baseline (2303.297 us; speedup 1.0000x reference)
//
#include <hip/hip_runtime.h>
#include <hip/hip_bf16.h>
#include <hip/hip_fp8.h>
#include <cstdint>

#define B_   128
#define T_   80
#define E_   100
#define U_   2048
#define G4_  8192

// scales: A-side (x,h) fp8 x16; B-side (weights) fp4 x64; acc * 1/1024
#define SA_    16.0f
#define SB4_   64.0f
#define INV_S_ (1.0f / 1024.0f)
#define SCL1_  0x7F7F7F7F   // E8M0 = 127 -> 2^0 per 32-block (x4 packed)

typedef __attribute__((ext_vector_type(4))) float f32x4;
typedef __attribute__((ext_vector_type(8))) int   i32x8;
typedef __attribute__((ext_vector_type(4))) int   i32x4;

__device__ __forceinline__ unsigned char f2fp8(float x) {
    __hip_fp8_e4m3 q(x);
    return q.__x;
}

// fp4 e2m1 quantize (round to nearest): values {0,.5,1,1.5,2,3,4,6}
__device__ __forceinline__ unsigned int q4(float x) {
    float a = fabsf(x);
    unsigned int s = (x < 0.f) ? 8u : 0u;
    unsigned int c = a < 0.25f ? 0u : a < 0.75f ? 1u : a < 1.25f ? 2u :
                     a < 1.75f ? 3u : a < 2.5f  ? 4u : a < 3.5f  ? 5u :
                     a < 5.0f  ? 6u : 7u;
    return s | c;
}

// pack 2 floats -> fp4 byte (HW convert if available)
__device__ __forceinline__ unsigned char pk4(float v0, float v1) {
#if __has_builtin(__builtin_amdgcn_cvt_scalef32_pk_fp4_f32)
    unsigned int w = __builtin_amdgcn_cvt_scalef32_pk_fp4_f32(0u, v0, v1, 1.0f, 0);
    return (unsigned char)(w & 0xFF);
#else
    return (unsigned char)(q4(v0) | (q4(v1) << 4));
#endif
}

// ---------------- embedding -> fp8 A-frag128 X: 1 window of K=128 -----------
__global__ __launch_bounds__(256)
void embed_pack(const int* __restrict__ tokens, const float* __restrict__ emb,
                unsigned char* __restrict__ Xp) {
    int gtid = blockIdx.x * 256 + threadIdx.x;   // one 8-byte chunk each
    if (gtid >= T_ * 8 * 64 * 4) return;
    int eb   = gtid & 3;
    int lane = (gtid >> 2) & 63;
    int mtg  = (gtid >> 8) & 7;
    int t    = gtid >> 11;
    int row  = (mtg >> 2) * 64 + (mtg & 3) * 16 + (lane & 15);
    const float* erow = emb + (size_t)tokens[row * T_ + t] * E_;
    unsigned char v[8];
#pragma unroll
    for (int j = 0; j < 8; ++j) {
        int k = (lane >> 4) * 32 + eb * 8 + j;
        v[j] = (k < E_) ? f2fp8(SA_ * erow[k]) : 0;
    }
    unsigned char* dst = Xp + ((size_t)(t * 8 + mtg)) * 2048 + lane * 32 + eb * 8;
    *reinterpret_cast<uint2*>(dst) = *reinterpret_cast<const uint2*>(v);
}

// ---------------- fused fp4 pack: coalesced reads, HW convert ---------------
__global__ __launch_bounds__(256)
void pack_all(const float* __restrict__ W0, const float* __restrict__ U0,
              const float* __restrict__ W1, const float* __restrict__ U1,
              const float* __restrict__ Wd,
              unsigned char* __restrict__ W0p, unsigned char* __restrict__ U0p,
              unsigned char* __restrict__ W1p, unsigned char* __restrict__ U1p,
              unsigned char* __restrict__ Wdp) {
    __shared__ float4 st4[32][65];   // [k-row][64 float4 cols + pad]
    const float* stf = reinterpret_cast<const float*>(&st4[0][0]);
    const int tid = threadIdx.x;
    int blk = blockIdx.x;
    const float* W; int K, Ncols, NG, NW; unsigned char* out; int lb;
    if (blk < 2048)      { W = U0; K = U_; Ncols = G4_; NG = 4; NW = 16; out = U0p; lb = blk; }
    else if (blk < 4096) { W = W1; K = U_; Ncols = G4_; NG = 4; NW = 16; out = W1p; lb = blk - 2048; }
    else if (blk < 6144) { W = U1; K = U_; Ncols = G4_; NG = 4; NW = 16; out = U1p; lb = blk - 4096; }
    else if (blk < 6272) { W = W0; K = E_; Ncols = G4_; NG = 4; NW = 1;  out = W0p; lb = blk - 6144; }
    else                 { W = Wd; K = U_; Ncols = U_;  NG = 1; NW = 16; out = Wdp; lb = blk - 6272; }

    int Wm, kg, cg;
    if (NW == 1) { Wm = 0;        kg = lb & 3;         cg = lb >> 2; }
    else         { Wm = lb & 15;  kg = (lb >> 4) & 3;  cg = lb >> 6; }
    int g, utb;
    if (NG == 4) { g = cg >> 3; utb = (cg & 7) * 16; }
    else         { g = 0;       utb = cg * 16; }
    const int cb = cg * 256;     // absolute col base (includes gate offset)

    // stage: reg-stage all 8 rows then write LDS (more loads in flight)
    {
        const int c4 = tid & 63;
        const int r0 = tid >> 6;
        float4 v[8];
#pragma unroll
        for (int p = 0; p < 8; ++p) {
            const int r = p * 4 + r0;
            const int k = Wm * 128 + kg * 32 + r;
            v[p] = make_float4(0.f, 0.f, 0.f, 0.f);
            if (k < K)
                v[p] = *reinterpret_cast<const float4*>(W + (size_t)k * Ncols + cb + c4 * 4);
        }
#pragma unroll
        for (int p = 0; p < 8; ++p) st4[p * 4 + r0][c4] = v[p];
    }
    __syncthreads();

    const int ut_l = tid >> 4;
    const int cl   = tid & 15;
    unsigned char v[16];
#pragma unroll
    for (int b = 0; b < 16; ++b) {
        float v0 = stf[((2 * b)     * 65 + (tid >> 2)) * 4 + (tid & 3)];
        float v1 = stf[((2 * b + 1) * 65 + (tid >> 2)) * 4 + (tid & 3)];
        v[b] = pk4(SB4_ * v0, SB4_ * v1);
    }
    const int ut = utb + ut_l;
    unsigned char* dst = out + (((size_t)(ut * NW + Wm)) * NG + g) * 1024 + (kg * 16 + cl) * 16;
    *reinterpret_cast<uint4*>(dst) = *reinterpret_cast<const uint4*>(v);
}

// ---------------- window-set load / MFMA-set helpers ------------------------
template<int NW0, int NW1>
__device__ __forceinline__ void ld_set(
    const unsigned char* __restrict__ a0, const unsigned char* __restrict__ a1,
    const unsigned char* __restrict__ b0, const unsigned char* __restrict__ b1,
    int w, i32x8 (&A)[4], i32x4 (&Bv)[4])
{
    if (w < NW0) {
#pragma unroll
        for (int mt = 0; mt < 4; ++mt)
            A[mt] = *reinterpret_cast<const i32x8*>(a0 + (size_t)(mt * NW0 + w) * 2048);
#pragma unroll
        for (int g = 0; g < 4; ++g)
            Bv[g] = *reinterpret_cast<const i32x4*>(b0 + (size_t)(w * 4 + g) * 1024);
    } else {
        int ww = w - NW0;
#pragma unroll
        for (int mt = 0; mt < 4; ++mt)
            A[mt] = *reinterpret_cast<const i32x8*>(a1 + (size_t)(mt * NW1 + ww) * 2048);
#pragma unroll
        for (int g = 0; g < 4; ++g)
            Bv[g] = *reinterpret_cast<const i32x4*>(b1 + (size_t)(ww * 4 + g) * 1024);
    }
}

__device__ __forceinline__ void ld_A(const unsigned char* __restrict__ a,
                                     int stride_nw, int w, i32x8 (&A)[4]) {
#pragma unroll
    for (int mt = 0; mt < 4; ++mt)
        A[mt] = *reinterpret_cast<const i32x8*>(a + (size_t)(mt * stride_nw + w) * 2048);
}

__device__ __forceinline__ void ld_B(const unsigned char* __restrict__ b,
                                     int w, i32x4 (&Bv)[4]) {
#pragma unroll
    for (int g = 0; g < 4; ++g)
        Bv[g] = *reinterpret_cast<const i32x4*>(b + (size_t)(w * 4 + g) * 1024);
}

__device__ __forceinline__ void mfma_set(f32x4 (&acc)[4][4], i32x8 (&A)[4], i32x4 (&Bv)[4]) {
    __builtin_amdgcn_s_setprio(1);
#pragma unroll
    for (int g = 0; g < 4; ++g) {
        i32x8 bf = {Bv[g][0], Bv[g][1], Bv[g][2], Bv[g][3], 0, 0, 0, 0};
#pragma unroll
        for (int mt = 0; mt < 4; ++mt)
            acc[g][mt] = __builtin_amdgcn_mfma_scale_f32_16x16x128_f8f6f4(
                A[mt], bf, acc[g][mt], 0, 4, 0, SCL1_, 0, SCL1_);
    }
    __builtin_amdgcn_s_setprio(0);
}

// ---------------- epilogue: 8-way kq reduction + cell update + packed h -----
__device__ __forceinline__ void epilogue(
    f32x4 (&acc)[4][4], const float* __restrict__ bias,
    float* __restrict__ c, unsigned char* __restrict__ h_out,
    float (*zs)[2][64][17], int ut, int mh, int tid, int lane, int kq)
{
    const int lr = tid >> 3;          // 0..63
    const int u0 = (tid & 7) * 2;     // 0,2,..,14
    const int grow = mh * 64 + lr;
    const int unit = ut * 16 + u0;

    // hoist independent global loads above the reduction barriers
    float2 cv = *reinterpret_cast<float2*>(&c[(size_t)grow * U_ + unit]);
    const float2 bi  = *reinterpret_cast<const float2*>(&bias[unit]);
    const float2 bfv = *reinterpret_cast<const float2*>(&bias[U_ + unit]);
    const float2 bgv = *reinterpret_cast<const float2*>(&bias[2 * U_ + unit]);
    const float2 bov = *reinterpret_cast<const float2*>(&bias[3 * U_ + unit]);

    float zg2[4][2];
#pragma unroll
    for (int rnd = 0; rnd < 2; ++rnd) {
        __syncthreads();
#pragma unroll
        for (int gg = 0; gg < 2; ++gg) {
            const int g = rnd * 2 + gg;
#pragma unroll
            for (int mt = 0; mt < 4; ++mt)
#pragma unroll
                for (int r = 0; r < 4; ++r)
                    zs[kq][gg][mt * 16 + (lane >> 4) * 4 + r][lane & 15] = acc[g][mt][r];
        }
        __syncthreads();
#pragma unroll
        for (int gg = 0; gg < 2; ++gg) {
            float s0 = 0.f, s1 = 0.f;
#pragma unroll
            for (int w8 = 0; w8 < 8; ++w8) {
                s0 += zs[w8][gg][lr][u0];
                s1 += zs[w8][gg][lr][u0 + 1];
            }
            zg2[rnd * 2 + gg][0] = s0;
            zg2[rnd * 2 + gg][1] = s1;
        }
    }

    float cn[2];
    unsigned char hv[2];
#pragma unroll
    for (int e = 0; e < 2; ++e) {
        float zi = zg2[0][e] * INV_S_ + (e ? bi.y : bi.x);
        float zf = zg2[1][e] * INV_S_ + (e ? bfv.y : bfv.x);
        float zg = zg2[2][e] * INV_S_ + (e ? bgv.y : bgv.x);
        float zo = zg2[3][e] * INV_S_ + (e ? bov.y : bov.x);
        float si = 1.f / (1.f + __expf(-zi));
        float sf = 1.f / (1.f + __expf(-zf));
        float so = 1.f / (1.f + __expf(-zo));
        float tg = tanhf(zg);
        float cc = sf * (e ? cv.y : cv.x) + si * tg;
        cn[e] = cc;
        hv[e] = f2fp8(SA_ * so * tanhf(cc));
    }
    *reinterpret_cast<float2*>(&c[(size_t)grow * U_ + unit]) = make_float2(cn[0], cn[1]);

    const int mt = lr >> 4;
    const int cl = lr & 15;
    const int Wh = unit >> 7;
    const int lg = (unit >> 5) & 3;
    const int e0 = unit & 31;            // even
    size_t fr = (size_t)(mh * 4 + mt) * 16 + Wh;
    uchar2 hv2; hv2.x = hv[0]; hv2.y = hv[1];
    *reinterpret_cast<uchar2*>(&h_out[fr * 2048 + (lg * 16 + cl) * 32 + e0]) = hv2;
}

// ---------------- prologue: L0(0) only (grid 256, XCD-swizzled) -------------
__global__ __launch_bounds__(512)
void lstm_l0_first(const unsigned char* __restrict__ Xp,
                   const unsigned char* __restrict__ W0p,
                   const unsigned char* __restrict__ U0p,
                   const float* __restrict__ b0,
                   float* __restrict__ c0,
                   const unsigned char* __restrict__ h0zero,
                   unsigned char* __restrict__ h0out) {
    __shared__ float zs[8][2][64][17];
    const int tid  = threadIdx.x;
    const int lane = tid & 63;
    const int kq   = tid >> 6;
    const int b    = blockIdx.x;
    const int s    = b >> 3;
    const int ut   = (b & 7) * 16 + (s >> 1);
    const int mh   = s & 1;

    const unsigned char* a0 = Xp     + ((size_t)(mh * 4) * 1)  * 2048 + lane * 32;
    const unsigned char* a1 = h0zero + ((size_t)(mh * 4) * 16) * 2048 + lane * 32;
    const unsigned char* p0 = W0p + ((size_t)(ut * 1)  * 4) * 1024 + lane * 16;
    const unsigned char* p1 = U0p + ((size_t)(ut * 16) * 4) * 1024 + lane * 16;

    f32x4 acc[4][4];
#pragma unroll
    for (int g = 0; g < 4; ++g)
#pragma unroll
        for (int mt = 0; mt < 4; ++mt) acc[g][mt] = f32x4{0.f, 0.f, 0.f, 0.f};

    i32x8 A0s[4], A1s[4], A2s[4];
    i32x4 B0s[4], B1s[4], B2s[4];
    ld_set<1, 16>(a0, a1, p0, p1, kq, A0s, B0s);
    ld_set<1, 16>(a0, a1, p0, p1, kq + 8, A1s, B1s);
    const bool tail = (kq + 16 < 17);
    if (tail) ld_set<1, 16>(a0, a1, p0, p1, kq + 16, A2s, B2s);
    mfma_set(acc, A0s, B0s);
    mfma_set(acc, A1s, B1s);
    if (tail) mfma_set(acc, A2s, B2s);

    epilogue(acc, b0, c0, h0out, zs, ut, mh, tid, lane, kq);
}

// ---------------- fused phase k: L1(k) sweep, L0(k+1) reusing h0 regs -------
__global__ __launch_bounds__(512)
void lstm_phase(const unsigned char* __restrict__ Xp,
                const unsigned char* __restrict__ W0p,
                const unsigned char* __restrict__ U0p,
                const unsigned char* __restrict__ W1p,
                const unsigned char* __restrict__ U1p,
                const float* __restrict__ b0,
                const float* __restrict__ b1,
                float* __restrict__ c0, float* __restrict__ c1,
                const unsigned char* __restrict__ h0cur,
                unsigned char* __restrict__ h0next,
                const unsigned char* __restrict__ h1in,
                unsigned char* __restrict__ h1out,
                int k) {
    __shared__ float zs[8][2][64][17];
    const int tid  = threadIdx.x;
    const int lane = tid & 63;
    const int kq   = tid >> 6;
    const int b    = blockIdx.x;
    const int s    = b >> 3;
    const int ut   = (b & 7) * 16 + (s >> 1);   // xcd owns 16 consecutive ut
    const int mh   = s & 1;
    const bool hasL0 = (k + 1 < T_);

    // L1 operand pointers; a0 = h0cur panel (windows 0..15), a1 = h1in
    const unsigned char* a0 = h0cur + ((size_t)(mh * 4) * 16) * 2048 + lane * 32;
    const unsigned char* a1 = h1in  + ((size_t)(mh * 4) * 16) * 2048 + lane * 32;
    const unsigned char* p0 = W1p + ((size_t)(ut * 16) * 4) * 1024 + lane * 16;
    const unsigned char* p1 = U1p + ((size_t)(ut * 16) * 4) * 1024 + lane * 16;
    // L0 operand pointers
    const unsigned char* l0x  = Xp + (size_t)(k + 1) * 8 * 2048
                                   + ((size_t)(mh * 4) * 1) * 2048 + lane * 32;
    const unsigned char* l0b0 = W0p + ((size_t)(ut * 1)  * 4) * 1024 + lane * 16;
    const unsigned char* l0b1 = U0p + ((size_t)(ut * 16) * 4) * 1024 + lane * 16;

    f32x4 acc[4][4];
#pragma unroll
    for (int g = 0; g < 4; ++g)
#pragma unroll
        for (int mt = 0; mt < 4; ++mt) acc[g][mt] = f32x4{0.f, 0.f, 0.f, 0.f};

    // L1 sweep: windows kq (h0), kq+8 (h0), kq+16 (h1), kq+24 (h1).
    // A0s/A1s hold the h0 fragments and stay live for the L0 sweep.
    i32x8 A0s[4], A1s[4], A2s[4], A3s[4];
    i32x4 B0s[4], B1s[4];
    i32x4 PB0[4], PB1[4], PBX[4];
    i32x8 PAX[4];

    ld_A(a0, 16, kq, A0s);       ld_B(p0, kq, B0s);
    ld_A(a0, 16, kq + 8, A1s);   ld_B(p0, kq + 8, B1s);
    ld_A(a1, 16, kq, A2s);       // h1 window kq+16 -> a1 local window kq
    mfma_set(acc, A0s, B0s);
    ld_B(p1, kq, B0s);           // U1 window kq (for A2s)
    ld_A(a1, 16, kq + 8, A3s);   // h1 window kq+24
    mfma_set(acc, A1s, B1s);
    ld_B(p1, kq + 8, B1s);       // U1 window kq+8 (for A3s)
    // L0 B prefetch — issued before the last two MFMA sets so their latency
    // hides under MFMA + the L1 epilogue
    if (hasL0) {
        ld_B(l0b1, kq, PB0);
        ld_B(l0b1, kq + 8, PB1);
        if (kq == 0) {
            ld_A(l0x, 1, 0, PAX);
            ld_B(l0b0, 0, PBX);
        }
    }
    mfma_set(acc, A2s, B0s);
    mfma_set(acc, A3s, B1s);

    // L1 epilogue (4 barriers)
    epilogue(acc, b1, c1, h1out, zs, ut, mh, tid, lane, kq);

    // L0 sweep: wave kq computes L0 windows kq+1 (=h0[kq], in A0s) and
    // kq+9 (=h0[kq+8], in A1s); wave 0 additionally window 0 (x, PAX).
    if (hasL0) {
#pragma unroll
        for (int g = 0; g < 4; ++g)
#pragma unroll
            for (int mt = 0; mt < 4; ++mt) acc[g][mt] = f32x4{0.f, 0.f, 0.f, 0.f};

        mfma_set(acc, A0s, PB0);
        mfma_set(acc, A1s, PB1);
        if (kq == 0) mfma_set(acc, PAX, PBX);

        epilogue(acc, b0, c0, h0next, zs, ut, mh, tid, lane, kq);
    }
}

// ---------------- head: y = relu((h1 @ Wd)/1024 + bd); fp8 x fp4 ------------
__global__ __launch_bounds__(256)
void head_mfma(const unsigned char* __restrict__ h1p,
               const unsigned char* __restrict__ Wdp,
               const float* __restrict__ bd, float* __restrict__ y) {
    const int lane = threadIdx.x & 63;
    const int w    = threadIdx.x >> 6;  // k-split wave
    const int ut   = blockIdx.x & 127;
    const int mh   = blockIdx.x >> 7;

    const unsigned char* ap = h1p + ((size_t)(mh * 4) * 16) * 2048 + lane * 32;
    const unsigned char* wp = Wdp + ((size_t)(ut * 16)) * 1024 + lane * 16;

    f32x4 acc[4];
#pragma unroll
    for (int mt = 0; mt < 4; ++mt) acc[mt] = f32x4{0.f, 0.f, 0.f, 0.f};

#pragma unroll
    for (int wi = 0; wi < 4; ++wi) {
        const int W = w + wi * 4;
        i32x4 bq = *reinterpret_cast<const i32x4*>(wp + (size_t)W * 1024);
        i32x8 bf = {bq[0], bq[1], bq[2], bq[3], 0, 0, 0, 0};
#pragma unroll
        for (int mt = 0; mt < 4; ++mt) {
            i32x8 a = *reinterpret_cast<const i32x8*>(ap + (size_t)(mt * 16 + W) * 2048);
            acc[mt] = __builtin_amdgcn_mfma_scale_f32_16x16x128_f8f6f4(
                a, bf, acc[mt], 0, 4, 0, SCL1_, 0, SCL1_);
        }
    }

    __shared__ float zs[4][64][17];
#pragma unroll
    for (int mt = 0; mt < 4; ++mt)
#pragma unroll
        for (int r = 0; r < 4; ++r)
            zs[w][mt * 16 + (lane >> 4) * 4 + r][lane & 15] = acc[mt][r];
    __syncthreads();

    const int tid = threadIdx.x;
    const int lr  = tid >> 2;
    const int u4  = (tid & 3) * 4;
    const int grow = mh * 64 + lr;
    const int gu   = ut * 16 + u4;

    float4 r;
    float* rr = &r.x;
#pragma unroll
    for (int e = 0; e < 4; ++e) {
        float v = (zs[0][lr][u4 + e] + zs[1][lr][u4 + e] +
                   zs[2][lr][u4 + e] + zs[3][lr][u4 + e]) * INV_S_ + bd[gu + e];
        rr[e] = v > 0.f ? v : 0.f;
    }
    *reinterpret_cast<float4*>(&y[(size_t)grow * U_ + gu]) = r;
}

// ---------------- out[b] = sigmoid(y[b,:] @ Wo + bo) ----------------
__global__ __launch_bounds__(256)
void head2(const float* __restrict__ y, const float* __restrict__ Wo,
           const float* __restrict__ bo, float* __restrict__ out) {
    __shared__ float red[256];
    const int b = blockIdx.x;
    const int tid = threadIdx.x;
    float s = 0.f;
    for (int u = tid; u < U_; u += 256) s += y[(size_t)b * U_ + u] * Wo[u];
    red[tid] = s;
    __syncthreads();
    for (int off = 128; off > 0; off >>= 1) {
        if (tid < off) red[tid] += red[tid + off];
        __syncthreads();
    }
    if (tid == 0) out[b] = 1.f / (1.f + __expf(-(red[0] + bo[0])));
}

extern "C" void kernel_launch(void* const* d_in, const int* in_sizes, int n_in,
                              void* d_out, int out_size, void* d_ws, size_t ws_size,
                              hipStream_t stream) {
    const int*   tokens = (const int*)  d_in[0];
    const float* emb    = (const float*)d_in[1];
    const float* W0     = (const float*)d_in[2];
    const float* U0     = (const float*)d_in[3];
    const float* b0     = (const float*)d_in[4];
    const float* W1     = (const float*)d_in[5];
    const float* U1     = (const float*)d_in[6];
    const float* b1     = (const float*)d_in[7];
    const float* Wd     = (const float*)d_in[8];
    const float* bd     = (const float*)d_in[9];
    const float* Wo     = (const float*)d_in[10];
    const float* bo     = (const float*)d_in[11];

    // ws layout (bytes); total ~32 MB
    char* base = (char*)d_ws;
    unsigned char* h0a = (unsigned char*)(base + 0);         // 256 KB (fp8 frag128)
    unsigned char* h1a = (unsigned char*)(base + 262144);    // 256 KB
    float*         c0  = (float*)        (base + 524288);    // 1 MB
    float*         c1  = (float*)        (base + 1572864);   // 1 MB
    unsigned char* h0b = (unsigned char*)(base + 2621440);   // 256 KB
    unsigned char* h1b = (unsigned char*)(base + 2883584);   // 256 KB
    unsigned char* Xp  = (unsigned char*)(base + 3145728);   // 1.25 MB
    float*         yb  = (float*)        (base + 3145728);   // overlays Xp (dead by head)
    unsigned char* W0p = (unsigned char*)(base + 4456448);   // 512 KB (fp4)
    unsigned char* U0p = (unsigned char*)(base + 4980736);   // 8 MB (fp4)
    unsigned char* W1p = (unsigned char*)(base + 13369344);  // 8 MB (fp4)
    unsigned char* U1p = (unsigned char*)(base + 21757952);  // 8 MB (fp4)
    unsigned char* Wdp = (unsigned char*)(base + 30146560);  // 2 MB (fp4)

    // zero h0a, h1a, c0, c1 (contiguous 2.56 MB)
    hipMemsetAsync(d_ws, 0, 2621440, stream);

    embed_pack<<<(T_ * 8 * 64 * 4 + 255) / 256, 256, 0, stream>>>(tokens, emb, Xp);
    pack_all<<<6784, 256, 0, stream>>>(W0, U0, W1, U1, Wd,
                                       W0p, U0p, W1p, U1p, Wdp);

    // prologue: L0(0): x(0) + h0a(=0) -> h0b
    lstm_l0_first<<<256, 512, 0, stream>>>(Xp, W0p, U0p, b0, c0, h0a, h0b);

    // fused phases: phase k = { L1(k), L0(k+1) }
    for (int k = 0; k < T_; ++k) {
        const unsigned char* h0cur  = (k & 1) ? h0a : h0b;
        unsigned char*       h0next = (k & 1) ? h0b : h0a;   // written for k+1
        const unsigned char* h1in   = (k & 1) ? h1b : h1a;
        unsigned char*       h1out  = (k & 1) ? h1a : h1b;
        lstm_phase<<<256, 512, 0, stream>>>(Xp, W0p, U0p, W1p, U1p,
                                            b0, b1, c0, c1,
                                            h0cur, h0next, h1in, h1out, k);
    }
    // h1(79): 79 odd -> h1a
    head_mfma<<<256, 256, 0, stream>>>(h1a, Wdp, bd, yb);
    head2<<<B_, 256, 0, stream>>>(yb, Wo, bo, (float*)d_out);
}

// Round 20
// 1071.074 us; speedup vs baseline: 2.1505x; 2.1505x over previous
//
#include <hip/hip_runtime.h>
#include <hip/hip_bf16.h>
#include <hip/hip_fp8.h>
#include <cstdint>

#define B_   128
#define T_   80
#define E_   100
#define U_   2048
#define G4_  8192

// scales: A-side (x,h) fp8 x16; B-side (weights) fp4 x64; acc * 1/1024
#define SA_    16.0f
#define SB4_   64.0f
#define INV_S_ (1.0f / 1024.0f)
#define SCL1_  0x7F7F7F7F   // E8M0 = 127 -> 2^0 per 32-block (x4 packed)

typedef __attribute__((ext_vector_type(4))) float f32x4;
typedef __attribute__((ext_vector_type(8))) int   i32x8;
typedef __attribute__((ext_vector_type(4))) int   i32x4;

__device__ __forceinline__ unsigned char f2fp8(float x) {
    __hip_fp8_e4m3 q(x);
    return q.__x;
}

// fp4 e2m1 quantize (round to nearest): values {0,.5,1,1.5,2,3,4,6}
__device__ __forceinline__ unsigned int q4(float x) {
    float a = fabsf(x);
    unsigned int s = (x < 0.f) ? 8u : 0u;
    unsigned int c = a < 0.25f ? 0u : a < 0.75f ? 1u : a < 1.25f ? 2u :
                     a < 1.75f ? 3u : a < 2.5f  ? 4u : a < 3.5f  ? 5u :
                     a < 5.0f  ? 6u : 7u;
    return s | c;
}

// pack 2 floats -> fp4 byte (HW convert if available)
__device__ __forceinline__ unsigned char pk4(float v0, float v1) {
#if __has_builtin(__builtin_amdgcn_cvt_scalef32_pk_fp4_f32)
    unsigned int w = __builtin_amdgcn_cvt_scalef32_pk_fp4_f32(0u, v0, v1, 1.0f, 0);
    return (unsigned char)(w & 0xFF);
#else
    return (unsigned char)(q4(v0) | (q4(v1) << 4));
#endif
}

// ---------------- embedding -> fp8 A-frag128 X: 1 window of K=128 -----------
__global__ __launch_bounds__(256)
void embed_pack(const int* __restrict__ tokens, const float* __restrict__ emb,
                unsigned char* __restrict__ Xp) {
    int gtid = blockIdx.x * 256 + threadIdx.x;   // one 8-byte chunk each
    if (gtid >= T_ * 8 * 64 * 4) return;
    int eb   = gtid & 3;
    int lane = (gtid >> 2) & 63;
    int mtg  = (gtid >> 8) & 7;
    int t    = gtid >> 11;
    int row  = (mtg >> 2) * 64 + (mtg & 3) * 16 + (lane & 15);
    const float* erow = emb + (size_t)tokens[row * T_ + t] * E_;
    unsigned char v[8];
#pragma unroll
    for (int j = 0; j < 8; ++j) {
        int k = (lane >> 4) * 32 + eb * 8 + j;
        v[j] = (k < E_) ? f2fp8(SA_ * erow[k]) : 0;
    }
    unsigned char* dst = Xp + ((size_t)(t * 8 + mtg)) * 2048 + lane * 32 + eb * 8;
    *reinterpret_cast<uint2*>(dst) = *reinterpret_cast<const uint2*>(v);
}

// ---------------- fused fp4 pack: coalesced reads, HW convert ---------------
__global__ __launch_bounds__(256)
void pack_all(const float* __restrict__ W0, const float* __restrict__ U0,
              const float* __restrict__ W1, const float* __restrict__ U1,
              const float* __restrict__ Wd,
              unsigned char* __restrict__ W0p, unsigned char* __restrict__ U0p,
              unsigned char* __restrict__ W1p, unsigned char* __restrict__ U1p,
              unsigned char* __restrict__ Wdp) {
    __shared__ float4 st4[32][65];   // [k-row][64 float4 cols + pad]
    const float* stf = reinterpret_cast<const float*>(&st4[0][0]);
    const int tid = threadIdx.x;
    int blk = blockIdx.x;
    const float* W; int K, Ncols, NG, NW; unsigned char* out; int lb;
    if (blk < 2048)      { W = U0; K = U_; Ncols = G4_; NG = 4; NW = 16; out = U0p; lb = blk; }
    else if (blk < 4096) { W = W1; K = U_; Ncols = G4_; NG = 4; NW = 16; out = W1p; lb = blk - 2048; }
    else if (blk < 6144) { W = U1; K = U_; Ncols = G4_; NG = 4; NW = 16; out = U1p; lb = blk - 4096; }
    else if (blk < 6272) { W = W0; K = E_; Ncols = G4_; NG = 4; NW = 1;  out = W0p; lb = blk - 6144; }
    else                 { W = Wd; K = U_; Ncols = U_;  NG = 1; NW = 16; out = Wdp; lb = blk - 6272; }

    int Wm, kg, cg;
    if (NW == 1) { Wm = 0;        kg = lb & 3;         cg = lb >> 2; }
    else         { Wm = lb & 15;  kg = (lb >> 4) & 3;  cg = lb >> 6; }
    int g, utb;
    if (NG == 4) { g = cg >> 3; utb = (cg & 7) * 16; }
    else         { g = 0;       utb = cg * 16; }
    const int cb = cg * 256;     // absolute col base (includes gate offset)

    // stage: reg-stage all 8 rows then write LDS (more loads in flight)
    {
        const int c4 = tid & 63;
        const int r0 = tid >> 6;
        float4 v[8];
#pragma unroll
        for (int p = 0; p < 8; ++p) {
            const int r = p * 4 + r0;
            const int k = Wm * 128 + kg * 32 + r;
            v[p] = make_float4(0.f, 0.f, 0.f, 0.f);
            if (k < K)
                v[p] = *reinterpret_cast<const float4*>(W + (size_t)k * Ncols + cb + c4 * 4);
        }
#pragma unroll
        for (int p = 0; p < 8; ++p) st4[p * 4 + r0][c4] = v[p];
    }
    __syncthreads();

    const int ut_l = tid >> 4;
    const int cl   = tid & 15;
    unsigned char v[16];
#pragma unroll
    for (int b = 0; b < 16; ++b) {
        float v0 = stf[((2 * b)     * 65 + (tid >> 2)) * 4 + (tid & 3)];
        float v1 = stf[((2 * b + 1) * 65 + (tid >> 2)) * 4 + (tid & 3)];
        v[b] = pk4(SB4_ * v0, SB4_ * v1);
    }
    const int ut = utb + ut_l;
    unsigned char* dst = out + (((size_t)(ut * NW + Wm)) * NG + g) * 1024 + (kg * 16 + cl) * 16;
    *reinterpret_cast<uint4*>(dst) = *reinterpret_cast<const uint4*>(v);
}

// ---------------- window-set load / MFMA-set helpers ------------------------
template<int NW0, int NW1>
__device__ __forceinline__ void ld_set(
    const unsigned char* __restrict__ a0, const unsigned char* __restrict__ a1,
    const unsigned char* __restrict__ b0, const unsigned char* __restrict__ b1,
    int w, i32x8 (&A)[4], i32x4 (&Bv)[4])
{
    if (w < NW0) {
#pragma unroll
        for (int mt = 0; mt < 4; ++mt)
            A[mt] = *reinterpret_cast<const i32x8*>(a0 + (size_t)(mt * NW0 + w) * 2048);
#pragma unroll
        for (int g = 0; g < 4; ++g)
            Bv[g] = *reinterpret_cast<const i32x4*>(b0 + (size_t)(w * 4 + g) * 1024);
    } else {
        int ww = w - NW0;
#pragma unroll
        for (int mt = 0; mt < 4; ++mt)
            A[mt] = *reinterpret_cast<const i32x8*>(a1 + (size_t)(mt * NW1 + ww) * 2048);
#pragma unroll
        for (int g = 0; g < 4; ++g)
            Bv[g] = *reinterpret_cast<const i32x4*>(b1 + (size_t)(ww * 4 + g) * 1024);
    }
}

__device__ __forceinline__ void ld_A(const unsigned char* __restrict__ a,
                                     int stride_nw, int w, i32x8 (&A)[4]) {
#pragma unroll
    for (int mt = 0; mt < 4; ++mt)
        A[mt] = *reinterpret_cast<const i32x8*>(a + (size_t)(mt * stride_nw + w) * 2048);
}

__device__ __forceinline__ void ld_B(const unsigned char* __restrict__ b,
                                     int w, i32x4 (&Bv)[4]) {
#pragma unroll
    for (int g = 0; g < 4; ++g)
        Bv[g] = *reinterpret_cast<const i32x4*>(b + (size_t)(w * 4 + g) * 1024);
}

__device__ __forceinline__ void mfma_set(f32x4 (&acc)[4][4], i32x8 (&A)[4], i32x4 (&Bv)[4]) {
    __builtin_amdgcn_s_setprio(1);
#pragma unroll
    for (int g = 0; g < 4; ++g) {
        i32x8 bf = {Bv[g][0], Bv[g][1], Bv[g][2], Bv[g][3], 0, 0, 0, 0};
#pragma unroll
        for (int mt = 0; mt < 4; ++mt)
            acc[g][mt] = __builtin_amdgcn_mfma_scale_f32_16x16x128_f8f6f4(
                A[mt], bf, acc[g][mt], 0, 4, 0, SCL1_, 0, SCL1_);
    }
    __builtin_amdgcn_s_setprio(0);
}

// ---------------- epilogue: 8-way kq reduction + cell update + packed h -----
__device__ __forceinline__ void epilogue(
    f32x4 (&acc)[4][4], const float* __restrict__ bias,
    float* __restrict__ c, unsigned char* __restrict__ h_out,
    float (*zs)[2][64][17], int ut, int mh, int tid, int lane, int kq)
{
    const int lr = tid >> 3;          // 0..63
    const int u0 = (tid & 7) * 2;     // 0,2,..,14
    float zg2[4][2];
#pragma unroll
    for (int rnd = 0; rnd < 2; ++rnd) {
        __syncthreads();
#pragma unroll
        for (int gg = 0; gg < 2; ++gg) {
            const int g = rnd * 2 + gg;
#pragma unroll
            for (int mt = 0; mt < 4; ++mt)
#pragma unroll
                for (int r = 0; r < 4; ++r)
                    zs[kq][gg][mt * 16 + (lane >> 4) * 4 + r][lane & 15] = acc[g][mt][r];
        }
        __syncthreads();
#pragma unroll
        for (int gg = 0; gg < 2; ++gg) {
            float s0 = 0.f, s1 = 0.f;
#pragma unroll
            for (int w8 = 0; w8 < 8; ++w8) {
                s0 += zs[w8][gg][lr][u0];
                s1 += zs[w8][gg][lr][u0 + 1];
            }
            zg2[rnd * 2 + gg][0] = s0;
            zg2[rnd * 2 + gg][1] = s1;
        }
    }

    const int grow = mh * 64 + lr;
    const int unit = ut * 16 + u0;
    const float2 bi  = *reinterpret_cast<const float2*>(&bias[unit]);
    const float2 bfv = *reinterpret_cast<const float2*>(&bias[U_ + unit]);
    const float2 bgv = *reinterpret_cast<const float2*>(&bias[2 * U_ + unit]);
    const float2 bov = *reinterpret_cast<const float2*>(&bias[3 * U_ + unit]);
    float2 cv = *reinterpret_cast<float2*>(&c[(size_t)grow * U_ + unit]);

    float cn[2];
    unsigned char hv[2];
#pragma unroll
    for (int e = 0; e < 2; ++e) {
        float zi = zg2[0][e] * INV_S_ + (e ? bi.y : bi.x);
        float zf = zg2[1][e] * INV_S_ + (e ? bfv.y : bfv.x);
        float zg = zg2[2][e] * INV_S_ + (e ? bgv.y : bgv.x);
        float zo = zg2[3][e] * INV_S_ + (e ? bov.y : bov.x);
        float si = 1.f / (1.f + __expf(-zi));
        float sf = 1.f / (1.f + __expf(-zf));
        float so = 1.f / (1.f + __expf(-zo));
        float tg = tanhf(zg);
        float cc = sf * (e ? cv.y : cv.x) + si * tg;
        cn[e] = cc;
        hv[e] = f2fp8(SA_ * so * tanhf(cc));
    }
    *reinterpret_cast<float2*>(&c[(size_t)grow * U_ + unit]) = make_float2(cn[0], cn[1]);

    const int mt = lr >> 4;
    const int cl = lr & 15;
    const int Wh = unit >> 7;
    const int lg = (unit >> 5) & 3;
    const int e0 = unit & 31;            // even
    size_t fr = (size_t)(mh * 4 + mt) * 16 + Wh;
    uchar2 hv2; hv2.x = hv[0]; hv2.y = hv[1];
    *reinterpret_cast<uchar2*>(&h_out[fr * 2048 + (lg * 16 + cl) * 32 + e0]) = hv2;
}

// ---------------- prologue: L0(0) only (grid 256, XCD-swizzled) -------------
__global__ __launch_bounds__(512)
void lstm_l0_first(const unsigned char* __restrict__ Xp,
                   const unsigned char* __restrict__ W0p,
                   const unsigned char* __restrict__ U0p,
                   const float* __restrict__ b0,
                   float* __restrict__ c0,
                   const unsigned char* __restrict__ h0zero,
                   unsigned char* __restrict__ h0out) {
    __shared__ float zs[8][2][64][17];
    const int tid  = threadIdx.x;
    const int lane = tid & 63;
    const int kq   = tid >> 6;
    const int b    = blockIdx.x;
    const int s    = b >> 3;
    const int ut   = (b & 7) * 16 + (s >> 1);
    const int mh   = s & 1;

    const unsigned char* a0 = Xp     + ((size_t)(mh * 4) * 1)  * 2048 + lane * 32;
    const unsigned char* a1 = h0zero + ((size_t)(mh * 4) * 16) * 2048 + lane * 32;
    const unsigned char* p0 = W0p + ((size_t)(ut * 1)  * 4) * 1024 + lane * 16;
    const unsigned char* p1 = U0p + ((size_t)(ut * 16) * 4) * 1024 + lane * 16;

    f32x4 acc[4][4];
#pragma unroll
    for (int g = 0; g < 4; ++g)
#pragma unroll
        for (int mt = 0; mt < 4; ++mt) acc[g][mt] = f32x4{0.f, 0.f, 0.f, 0.f};

    i32x8 A0s[4], A1s[4], A2s[4];
    i32x4 B0s[4], B1s[4], B2s[4];
    ld_set<1, 16>(a0, a1, p0, p1, kq, A0s, B0s);
    ld_set<1, 16>(a0, a1, p0, p1, kq + 8, A1s, B1s);
    const bool tail = (kq + 16 < 17);
    if (tail) ld_set<1, 16>(a0, a1, p0, p1, kq + 16, A2s, B2s);
    mfma_set(acc, A0s, B0s);
    mfma_set(acc, A1s, B1s);
    if (tail) mfma_set(acc, A2s, B2s);

    epilogue(acc, b0, c0, h0out, zs, ut, mh, tid, lane, kq);
}

// ---------------- fused phase k: L1(k) sweep, L0(k+1) reusing h0 regs -------
__global__ __launch_bounds__(512)
void lstm_phase(const unsigned char* __restrict__ Xp,
                const unsigned char* __restrict__ W0p,
                const unsigned char* __restrict__ U0p,
                const unsigned char* __restrict__ W1p,
                const unsigned char* __restrict__ U1p,
                const float* __restrict__ b0,
                const float* __restrict__ b1,
                float* __restrict__ c0, float* __restrict__ c1,
                const unsigned char* __restrict__ h0cur,
                unsigned char* __restrict__ h0next,
                const unsigned char* __restrict__ h1in,
                unsigned char* __restrict__ h1out,
                int k) {
    __shared__ float zs[8][2][64][17];
    const int tid  = threadIdx.x;
    const int lane = tid & 63;
    const int kq   = tid >> 6;
    const int b    = blockIdx.x;
    const int s    = b >> 3;
    const int ut   = (b & 7) * 16 + (s >> 1);   // xcd owns 16 consecutive ut
    const int mh   = s & 1;
    const bool hasL0 = (k + 1 < T_);

    // L1 operand pointers; a0 = h0cur panel (windows 0..15), a1 = h1in
    const unsigned char* a0 = h0cur + ((size_t)(mh * 4) * 16) * 2048 + lane * 32;
    const unsigned char* a1 = h1in  + ((size_t)(mh * 4) * 16) * 2048 + lane * 32;
    const unsigned char* p0 = W1p + ((size_t)(ut * 16) * 4) * 1024 + lane * 16;
    const unsigned char* p1 = U1p + ((size_t)(ut * 16) * 4) * 1024 + lane * 16;
    // L0 operand pointers
    const unsigned char* l0x  = Xp + (size_t)(k + 1) * 8 * 2048
                                   + ((size_t)(mh * 4) * 1) * 2048 + lane * 32;
    const unsigned char* l0b0 = W0p + ((size_t)(ut * 1)  * 4) * 1024 + lane * 16;
    const unsigned char* l0b1 = U0p + ((size_t)(ut * 16) * 4) * 1024 + lane * 16;

    f32x4 acc[4][4];
#pragma unroll
    for (int g = 0; g < 4; ++g)
#pragma unroll
        for (int mt = 0; mt < 4; ++mt) acc[g][mt] = f32x4{0.f, 0.f, 0.f, 0.f};

    // L1 sweep: windows kq (h0), kq+8 (h0), kq+16 (h1), kq+24 (h1).
    // A0s/A1s hold the h0 fragments and stay live for the L0 sweep.
    i32x8 A0s[4], A1s[4], A2s[4], A3s[4];
    i32x4 B0s[4], B1s[4];
    ld_A(a0, 16, kq, A0s);       ld_B(p0, kq, B0s);
    ld_A(a0, 16, kq + 8, A1s);   ld_B(p0, kq + 8, B1s);
    ld_A(a1, 16, kq, A2s);       // h1 window kq+16 -> a1 local window kq
    mfma_set(acc, A0s, B0s);
    ld_B(p1, kq, B0s);           // U1 window kq (for A2s)
    ld_A(a1, 16, kq + 8, A3s);   // h1 window kq+24
    mfma_set(acc, A1s, B1s);
    ld_B(p1, kq + 8, B1s);       // U1 window kq+8 (for A3s)
    mfma_set(acc, A2s, B0s);
    mfma_set(acc, A3s, B1s);

    // L0 B prefetch (hides under L1 epilogue): U0 windows kq, kq+8; wave0: x+W0
    i32x4 PB0[4], PB1[4], PBX[4];
    i32x8 PAX[4];
    if (hasL0) {
        ld_B(l0b1, kq, PB0);
        ld_B(l0b1, kq + 8, PB1);
        if (kq == 0) {
            ld_A(l0x, 1, 0, PAX);
            ld_B(l0b0, 0, PBX);
        }
    }

    // L1 epilogue (4 barriers)
    epilogue(acc, b1, c1, h1out, zs, ut, mh, tid, lane, kq);

    // L0 sweep: wave kq computes L0 windows kq+1 (=h0[kq], in A0s) and
    // kq+9 (=h0[kq+8], in A1s); wave 0 additionally window 0 (x, PAX).
    if (hasL0) {
#pragma unroll
        for (int g = 0; g < 4; ++g)
#pragma unroll
            for (int mt = 0; mt < 4; ++mt) acc[g][mt] = f32x4{0.f, 0.f, 0.f, 0.f};

        mfma_set(acc, A0s, PB0);
        mfma_set(acc, A1s, PB1);
        if (kq == 0) mfma_set(acc, PAX, PBX);

        epilogue(acc, b0, c0, h0next, zs, ut, mh, tid, lane, kq);
    }
}

// ---------------- head: y = relu((h1 @ Wd)/1024 + bd); fp8 x fp4 ------------
__global__ __launch_bounds__(256)
void head_mfma(const unsigned char* __restrict__ h1p,
               const unsigned char* __restrict__ Wdp,
               const float* __restrict__ bd, float* __restrict__ y) {
    const int lane = threadIdx.x & 63;
    const int w    = threadIdx.x >> 6;  // k-split wave
    const int ut   = blockIdx.x & 127;
    const int mh   = blockIdx.x >> 7;

    const unsigned char* ap = h1p + ((size_t)(mh * 4) * 16) * 2048 + lane * 32;
    const unsigned char* wp = Wdp + ((size_t)(ut * 16)) * 1024 + lane * 16;

    f32x4 acc[4];
#pragma unroll
    for (int mt = 0; mt < 4; ++mt) acc[mt] = f32x4{0.f, 0.f, 0.f, 0.f};

#pragma unroll
    for (int wi = 0; wi < 4; ++wi) {
        const int W = w + wi * 4;
        i32x4 bq = *reinterpret_cast<const i32x4*>(wp + (size_t)W * 1024);
        i32x8 bf = {bq[0], bq[1], bq[2], bq[3], 0, 0, 0, 0};
#pragma unroll
        for (int mt = 0; mt < 4; ++mt) {
            i32x8 a = *reinterpret_cast<const i32x8*>(ap + (size_t)(mt * 16 + W) * 2048);
            acc[mt] = __builtin_amdgcn_mfma_scale_f32_16x16x128_f8f6f4(
                a, bf, acc[mt], 0, 4, 0, SCL1_, 0, SCL1_);
        }
    }

    __shared__ float zs[4][64][17];
#pragma unroll
    for (int mt = 0; mt < 4; ++mt)
#pragma unroll
        for (int r = 0; r < 4; ++r)
            zs[w][mt * 16 + (lane >> 4) * 4 + r][lane & 15] = acc[mt][r];
    __syncthreads();

    const int tid = threadIdx.x;
    const int lr  = tid >> 2;
    const int u4  = (tid & 3) * 4;
    const int grow = mh * 64 + lr;
    const int gu   = ut * 16 + u4;

    float4 r;
    float* rr = &r.x;
#pragma unroll
    for (int e = 0; e < 4; ++e) {
        float v = (zs[0][lr][u4 + e] + zs[1][lr][u4 + e] +
                   zs[2][lr][u4 + e] + zs[3][lr][u4 + e]) * INV_S_ + bd[gu + e];
        rr[e] = v > 0.f ? v : 0.f;
    }
    *reinterpret_cast<float4*>(&y[(size_t)grow * U_ + gu]) = r;
}

// ---------------- out[b] = sigmoid(y[b,:] @ Wo + bo) ----------------
__global__ __launch_bounds__(256)
void head2(const float* __restrict__ y, const float* __restrict__ Wo,
           const float* __restrict__ bo, float* __restrict__ out) {
    __shared__ float red[256];
    const int b = blockIdx.x;
    const int tid = threadIdx.x;
    float s = 0.f;
    for (int u = tid; u < U_; u += 256) s += y[(size_t)b * U_ + u] * Wo[u];
    red[tid] = s;
    __syncthreads();
    for (int off = 128; off > 0; off >>= 1) {
        if (tid < off) red[tid] += red[tid + off];
        __syncthreads();
    }
    if (tid == 0) out[b] = 1.f / (1.f + __expf(-(red[0] + bo[0])));
}

extern "C" void kernel_launch(void* const* d_in, const int* in_sizes, int n_in,
                              void* d_out, int out_size, void* d_ws, size_t ws_size,
                              hipStream_t stream) {
    const int*   tokens = (const int*)  d_in[0];
    const float* emb    = (const float*)d_in[1];
    const float* W0     = (const float*)d_in[2];
    const float* U0     = (const float*)d_in[3];
    const float* b0     = (const float*)d_in[4];
    const float* W1     = (const float*)d_in[5];
    const float* U1     = (const float*)d_in[6];
    const float* b1     = (const float*)d_in[7];
    const float* Wd     = (const float*)d_in[8];
    const float* bd     = (const float*)d_in[9];
    const float* Wo     = (const float*)d_in[10];
    const float* bo     = (const float*)d_in[11];

    // ws layout (bytes); total ~32 MB
    char* base = (char*)d_ws;
    unsigned char* h0a = (unsigned char*)(base + 0);         // 256 KB (fp8 frag128)
    unsigned char* h1a = (unsigned char*)(base + 262144);    // 256 KB
    float*         c0  = (float*)        (base + 524288);    // 1 MB
    float*         c1  = (float*)        (base + 1572864);   // 1 MB
    unsigned char* h0b = (unsigned char*)(base + 2621440);   // 256 KB
    unsigned char* h1b = (unsigned char*)(base + 2883584);   // 256 KB
    unsigned char* Xp  = (unsigned char*)(base + 3145728);   // 1.25 MB
    float*         yb  = (float*)        (base + 3145728);   // overlays Xp (dead by head)
    unsigned char* W0p = (unsigned char*)(base + 4456448);   // 512 KB (fp4)
    unsigned char* U0p = (unsigned char*)(base + 4980736);   // 8 MB (fp4)
    unsigned char* W1p = (unsigned char*)(base + 13369344);  // 8 MB (fp4)
    unsigned char* U1p = (unsigned char*)(base + 21757952);  // 8 MB (fp4)
    unsigned char* Wdp = (unsigned char*)(base + 30146560);  // 2 MB (fp4)

    // zero h0a, h1a, c0, c1 (contiguous 2.56 MB)
    hipMemsetAsync(d_ws, 0, 2621440, stream);

    embed_pack<<<(T_ * 8 * 64 * 4 + 255) / 256, 256, 0, stream>>>(tokens, emb, Xp);
    pack_all<<<6784, 256, 0, stream>>>(W0, U0, W1, U1, Wd,
                                       W0p, U0p, W1p, U1p, Wdp);

    // prologue: L0(0): x(0) + h0a(=0) -> h0b
    lstm_l0_first<<<256, 512, 0, stream>>>(Xp, W0p, U0p, b0, c0, h0a, h0b);

    // fused phases: phase k = { L1(k), L0(k+1) }
    for (int k = 0; k < T_; ++k) {
        const unsigned char* h0cur  = (k & 1) ? h0a : h0b;
        unsigned char*       h0next = (k & 1) ? h0b : h0a;   // written for k+1
        const unsigned char* h1in   = (k & 1) ? h1b : h1a;
        unsigned char*       h1out  = (k & 1) ? h1a : h1b;
        lstm_phase<<<256, 512, 0, stream>>>(Xp, W0p, U0p, W1p, U1p,
                                            b0, b1, c0, c1,
                                            h0cur, h0next, h1in, h1out, k);
    }
    // h1(79): 79 odd -> h1a
    head_mfma<<<256, 256, 0, stream>>>(h1a, Wdp, bd, yb);
    head2<<<B_, 256, 0, stream>>>(yb, Wo, bo, (float*)d_out);
}

// Round 21
// 1044.379 us; speedup vs baseline: 2.2054x; 1.0256x over previous
//
#include <hip/hip_runtime.h>
#include <hip/hip_bf16.h>
#include <hip/hip_fp8.h>
#include <cstdint>

#define B_   128
#define T_   80
#define E_   100
#define U_   2048
#define G4_  8192

// scales: A-side (x,h) fp8 x16; B-side (weights) fp4 x64; acc * 1/1024
#define SA_    16.0f
#define SB4_   64.0f
#define INV_S_ (1.0f / 1024.0f)
#define SCL1_  0x7F7F7F7F   // E8M0 = 127 -> 2^0 per 32-block (x4 packed)

typedef __attribute__((ext_vector_type(4))) float f32x4;
typedef __attribute__((ext_vector_type(8))) int   i32x8;
typedef __attribute__((ext_vector_type(4))) int   i32x4;

__device__ __forceinline__ unsigned char f2fp8(float x) {
    __hip_fp8_e4m3 q(x);
    return q.__x;
}

// fp4 e2m1 quantize (round to nearest): values {0,.5,1,1.5,2,3,4,6}
__device__ __forceinline__ unsigned int q4(float x) {
    float a = fabsf(x);
    unsigned int s = (x < 0.f) ? 8u : 0u;
    unsigned int c = a < 0.25f ? 0u : a < 0.75f ? 1u : a < 1.25f ? 2u :
                     a < 1.75f ? 3u : a < 2.5f  ? 4u : a < 3.5f  ? 5u :
                     a < 5.0f  ? 6u : 7u;
    return s | c;
}

// pack 2 floats -> fp4 byte (HW convert if available)
__device__ __forceinline__ unsigned char pk4(float v0, float v1) {
#if __has_builtin(__builtin_amdgcn_cvt_scalef32_pk_fp4_f32)
    unsigned int w = __builtin_amdgcn_cvt_scalef32_pk_fp4_f32(0u, v0, v1, 1.0f, 0);
    return (unsigned char)(w & 0xFF);
#else
    return (unsigned char)(q4(v0) | (q4(v1) << 4));
#endif
}

// ---------------- embedding -> fp8 A-frag128 X: 1 window of K=128 -----------
__global__ __launch_bounds__(256)
void embed_pack(const int* __restrict__ tokens, const float* __restrict__ emb,
                unsigned char* __restrict__ Xp) {
    int gtid = blockIdx.x * 256 + threadIdx.x;   // one 8-byte chunk each
    if (gtid >= T_ * 8 * 64 * 4) return;
    int eb   = gtid & 3;
    int lane = (gtid >> 2) & 63;
    int mtg  = (gtid >> 8) & 7;
    int t    = gtid >> 11;
    int row  = (mtg >> 2) * 64 + (mtg & 3) * 16 + (lane & 15);
    const float* erow = emb + (size_t)tokens[row * T_ + t] * E_;
    unsigned char v[8];
#pragma unroll
    for (int j = 0; j < 8; ++j) {
        int k = (lane >> 4) * 32 + eb * 8 + j;
        v[j] = (k < E_) ? f2fp8(SA_ * erow[k]) : 0;
    }
    unsigned char* dst = Xp + ((size_t)(t * 8 + mtg)) * 2048 + lane * 32 + eb * 8;
    *reinterpret_cast<uint2*>(dst) = *reinterpret_cast<const uint2*>(v);
}

// ---------------- fused fp4 pack: coalesced reads, HW convert ---------------
__global__ __launch_bounds__(256)
void pack_all(const float* __restrict__ W0, const float* __restrict__ U0,
              const float* __restrict__ W1, const float* __restrict__ U1,
              const float* __restrict__ Wd,
              unsigned char* __restrict__ W0p, unsigned char* __restrict__ U0p,
              unsigned char* __restrict__ W1p, unsigned char* __restrict__ U1p,
              unsigned char* __restrict__ Wdp) {
    __shared__ float4 st4[32][65];   // [k-row][64 float4 cols + pad]
    const float* stf = reinterpret_cast<const float*>(&st4[0][0]);
    const int tid = threadIdx.x;
    int blk = blockIdx.x;
    const float* W; int K, Ncols, NG, NW; unsigned char* out; int lb;
    if (blk < 2048)      { W = U0; K = U_; Ncols = G4_; NG = 4; NW = 16; out = U0p; lb = blk; }
    else if (blk < 4096) { W = W1; K = U_; Ncols = G4_; NG = 4; NW = 16; out = W1p; lb = blk - 2048; }
    else if (blk < 6144) { W = U1; K = U_; Ncols = G4_; NG = 4; NW = 16; out = U1p; lb = blk - 4096; }
    else if (blk < 6272) { W = W0; K = E_; Ncols = G4_; NG = 4; NW = 1;  out = W0p; lb = blk - 6144; }
    else                 { W = Wd; K = U_; Ncols = U_;  NG = 1; NW = 16; out = Wdp; lb = blk - 6272; }

    int Wm, kg, cg;
    if (NW == 1) { Wm = 0;        kg = lb & 3;         cg = lb >> 2; }
    else         { Wm = lb & 15;  kg = (lb >> 4) & 3;  cg = lb >> 6; }
    int g, utb;
    if (NG == 4) { g = cg >> 3; utb = (cg & 7) * 16; }
    else         { g = 0;       utb = cg * 16; }
    const int cb = cg * 256;     // absolute col base (includes gate offset)

    // stage: reg-stage all 8 rows then write LDS (more loads in flight)
    {
        const int c4 = tid & 63;
        const int r0 = tid >> 6;
        float4 v[8];
#pragma unroll
        for (int p = 0; p < 8; ++p) {
            const int r = p * 4 + r0;
            const int k = Wm * 128 + kg * 32 + r;
            v[p] = make_float4(0.f, 0.f, 0.f, 0.f);
            if (k < K)
                v[p] = *reinterpret_cast<const float4*>(W + (size_t)k * Ncols + cb + c4 * 4);
        }
#pragma unroll
        for (int p = 0; p < 8; ++p) st4[p * 4 + r0][c4] = v[p];
    }
    __syncthreads();

    const int ut_l = tid >> 4;
    const int cl   = tid & 15;
    unsigned char v[16];
#pragma unroll
    for (int b = 0; b < 16; ++b) {
        float v0 = stf[((2 * b)     * 65 + (tid >> 2)) * 4 + (tid & 3)];
        float v1 = stf[((2 * b + 1) * 65 + (tid >> 2)) * 4 + (tid & 3)];
        v[b] = pk4(SB4_ * v0, SB4_ * v1);
    }
    const int ut = utb + ut_l;
    unsigned char* dst = out + (((size_t)(ut * NW + Wm)) * NG + g) * 1024 + (kg * 16 + cl) * 16;
    *reinterpret_cast<uint4*>(dst) = *reinterpret_cast<const uint4*>(v);
}

// ---------------- window-set load / MFMA-set helpers ------------------------
template<int NW0, int NW1>
__device__ __forceinline__ void ld_set(
    const unsigned char* __restrict__ a0, const unsigned char* __restrict__ a1,
    const unsigned char* __restrict__ b0, const unsigned char* __restrict__ b1,
    int w, i32x8 (&A)[4], i32x4 (&Bv)[4])
{
    if (w < NW0) {
#pragma unroll
        for (int mt = 0; mt < 4; ++mt)
            A[mt] = *reinterpret_cast<const i32x8*>(a0 + (size_t)(mt * NW0 + w) * 2048);
#pragma unroll
        for (int g = 0; g < 4; ++g)
            Bv[g] = *reinterpret_cast<const i32x4*>(b0 + (size_t)(w * 4 + g) * 1024);
    } else {
        int ww = w - NW0;
#pragma unroll
        for (int mt = 0; mt < 4; ++mt)
            A[mt] = *reinterpret_cast<const i32x8*>(a1 + (size_t)(mt * NW1 + ww) * 2048);
#pragma unroll
        for (int g = 0; g < 4; ++g)
            Bv[g] = *reinterpret_cast<const i32x4*>(b1 + (size_t)(ww * 4 + g) * 1024);
    }
}

__device__ __forceinline__ void ld_A(const unsigned char* __restrict__ a,
                                     int stride_nw, int w, i32x8 (&A)[4]) {
#pragma unroll
    for (int mt = 0; mt < 4; ++mt)
        A[mt] = *reinterpret_cast<const i32x8*>(a + (size_t)(mt * stride_nw + w) * 2048);
}

__device__ __forceinline__ void ld_B(const unsigned char* __restrict__ b,
                                     int w, i32x4 (&Bv)[4]) {
#pragma unroll
    for (int g = 0; g < 4; ++g)
        Bv[g] = *reinterpret_cast<const i32x4*>(b + (size_t)(w * 4 + g) * 1024);
}

__device__ __forceinline__ void mfma_set(f32x4 (&acc)[4][4], i32x8 (&A)[4], i32x4 (&Bv)[4]) {
    __builtin_amdgcn_s_setprio(1);
#pragma unroll
    for (int g = 0; g < 4; ++g) {
        i32x8 bf = {Bv[g][0], Bv[g][1], Bv[g][2], Bv[g][3], 0, 0, 0, 0};
#pragma unroll
        for (int mt = 0; mt < 4; ++mt)
            acc[g][mt] = __builtin_amdgcn_mfma_scale_f32_16x16x128_f8f6f4(
                A[mt], bf, acc[g][mt], 0, 4, 0, SCL1_, 0, SCL1_);
    }
    __builtin_amdgcn_s_setprio(0);
}

// ---------------- epilogue: single-round 8-way reduction + cell update ------
// zs[8][4][64][17] = 139 KB: all 4 gates exchanged in one barrier pair.
__device__ __forceinline__ void epilogue(
    f32x4 (&acc)[4][4], const float* __restrict__ bias,
    float* __restrict__ c, unsigned char* __restrict__ h_out,
    float (*zs)[4][64][17], int ut, int mh, int tid, int lane, int kq)
{
    const int lr = tid >> 3;          // 0..63
    const int u0 = (tid & 7) * 2;     // 0,2,..,14

    __syncthreads();   // prior zs use complete
#pragma unroll
    for (int g = 0; g < 4; ++g)
#pragma unroll
        for (int mt = 0; mt < 4; ++mt)
#pragma unroll
            for (int r = 0; r < 4; ++r)
                zs[kq][g][mt * 16 + (lane >> 4) * 4 + r][lane & 15] = acc[g][mt][r];
    __syncthreads();

    float zg2[4][2];
#pragma unroll
    for (int g = 0; g < 4; ++g) {
        float s0 = 0.f, s1 = 0.f;
#pragma unroll
        for (int w8 = 0; w8 < 8; ++w8) {
            s0 += zs[w8][g][lr][u0];
            s1 += zs[w8][g][lr][u0 + 1];
        }
        zg2[g][0] = s0;
        zg2[g][1] = s1;
    }

    const int grow = mh * 64 + lr;
    const int unit = ut * 16 + u0;
    const float2 bi  = *reinterpret_cast<const float2*>(&bias[unit]);
    const float2 bfv = *reinterpret_cast<const float2*>(&bias[U_ + unit]);
    const float2 bgv = *reinterpret_cast<const float2*>(&bias[2 * U_ + unit]);
    const float2 bov = *reinterpret_cast<const float2*>(&bias[3 * U_ + unit]);
    float2 cv = *reinterpret_cast<float2*>(&c[(size_t)grow * U_ + unit]);

    float cn[2];
    unsigned char hv[2];
#pragma unroll
    for (int e = 0; e < 2; ++e) {
        float zi = zg2[0][e] * INV_S_ + (e ? bi.y : bi.x);
        float zf = zg2[1][e] * INV_S_ + (e ? bfv.y : bfv.x);
        float zg = zg2[2][e] * INV_S_ + (e ? bgv.y : bgv.x);
        float zo = zg2[3][e] * INV_S_ + (e ? bov.y : bov.x);
        float si = 1.f / (1.f + __expf(-zi));
        float sf = 1.f / (1.f + __expf(-zf));
        float so = 1.f / (1.f + __expf(-zo));
        float tg = tanhf(zg);
        float cc = sf * (e ? cv.y : cv.x) + si * tg;
        cn[e] = cc;
        hv[e] = f2fp8(SA_ * so * tanhf(cc));
    }
    *reinterpret_cast<float2*>(&c[(size_t)grow * U_ + unit]) = make_float2(cn[0], cn[1]);

    const int mt = lr >> 4;
    const int cl = lr & 15;
    const int Wh = unit >> 7;
    const int lg = (unit >> 5) & 3;
    const int e0 = unit & 31;            // even
    size_t fr = (size_t)(mh * 4 + mt) * 16 + Wh;
    uchar2 hv2; hv2.x = hv[0]; hv2.y = hv[1];
    *reinterpret_cast<uchar2*>(&h_out[fr * 2048 + (lg * 16 + cl) * 32 + e0]) = hv2;
}

// ---------------- prologue: L0(0) only (grid 256, XCD-swizzled) -------------
__global__ __launch_bounds__(512)
void lstm_l0_first(const unsigned char* __restrict__ Xp,
                   const unsigned char* __restrict__ W0p,
                   const unsigned char* __restrict__ U0p,
                   const float* __restrict__ b0,
                   float* __restrict__ c0,
                   const unsigned char* __restrict__ h0zero,
                   unsigned char* __restrict__ h0out) {
    __shared__ float zs[8][4][64][17];
    const int tid  = threadIdx.x;
    const int lane = tid & 63;
    const int kq   = tid >> 6;
    const int b    = blockIdx.x;
    const int s    = b >> 3;
    const int ut   = (b & 7) * 16 + (s >> 1);
    const int mh   = s & 1;

    const unsigned char* a0 = Xp     + ((size_t)(mh * 4) * 1)  * 2048 + lane * 32;
    const unsigned char* a1 = h0zero + ((size_t)(mh * 4) * 16) * 2048 + lane * 32;
    const unsigned char* p0 = W0p + ((size_t)(ut * 1)  * 4) * 1024 + lane * 16;
    const unsigned char* p1 = U0p + ((size_t)(ut * 16) * 4) * 1024 + lane * 16;

    f32x4 acc[4][4];
#pragma unroll
    for (int g = 0; g < 4; ++g)
#pragma unroll
        for (int mt = 0; mt < 4; ++mt) acc[g][mt] = f32x4{0.f, 0.f, 0.f, 0.f};

    i32x8 A0s[4], A1s[4], A2s[4];
    i32x4 B0s[4], B1s[4], B2s[4];
    ld_set<1, 16>(a0, a1, p0, p1, kq, A0s, B0s);
    ld_set<1, 16>(a0, a1, p0, p1, kq + 8, A1s, B1s);
    const bool tail = (kq + 16 < 17);
    if (tail) ld_set<1, 16>(a0, a1, p0, p1, kq + 16, A2s, B2s);
    mfma_set(acc, A0s, B0s);
    mfma_set(acc, A1s, B1s);
    if (tail) mfma_set(acc, A2s, B2s);

    epilogue(acc, b0, c0, h0out, zs, ut, mh, tid, lane, kq);
}

// ---------------- fused phase k: L1(k) sweep, L0(k+1) reusing h0 regs -------
__global__ __launch_bounds__(512)
void lstm_phase(const unsigned char* __restrict__ Xp,
                const unsigned char* __restrict__ W0p,
                const unsigned char* __restrict__ U0p,
                const unsigned char* __restrict__ W1p,
                const unsigned char* __restrict__ U1p,
                const float* __restrict__ b0,
                const float* __restrict__ b1,
                float* __restrict__ c0, float* __restrict__ c1,
                const unsigned char* __restrict__ h0cur,
                unsigned char* __restrict__ h0next,
                const unsigned char* __restrict__ h1in,
                unsigned char* __restrict__ h1out,
                int k) {
    __shared__ float zs[8][4][64][17];
    const int tid  = threadIdx.x;
    const int lane = tid & 63;
    const int kq   = tid >> 6;
    const int b    = blockIdx.x;
    const int s    = b >> 3;
    const int ut   = (b & 7) * 16 + (s >> 1);   // xcd owns 16 consecutive ut
    const int mh   = s & 1;
    const bool hasL0 = (k + 1 < T_);

    // L1 operand pointers; a0 = h0cur panel (windows 0..15), a1 = h1in
    const unsigned char* a0 = h0cur + ((size_t)(mh * 4) * 16) * 2048 + lane * 32;
    const unsigned char* a1 = h1in  + ((size_t)(mh * 4) * 16) * 2048 + lane * 32;
    const unsigned char* p0 = W1p + ((size_t)(ut * 16) * 4) * 1024 + lane * 16;
    const unsigned char* p1 = U1p + ((size_t)(ut * 16) * 4) * 1024 + lane * 16;
    // L0 operand pointers
    const unsigned char* l0x  = Xp + (size_t)(k + 1) * 8 * 2048
                                   + ((size_t)(mh * 4) * 1) * 2048 + lane * 32;
    const unsigned char* l0b0 = W0p + ((size_t)(ut * 1)  * 4) * 1024 + lane * 16;
    const unsigned char* l0b1 = U0p + ((size_t)(ut * 16) * 4) * 1024 + lane * 16;

    f32x4 acc[4][4];
#pragma unroll
    for (int g = 0; g < 4; ++g)
#pragma unroll
        for (int mt = 0; mt < 4; ++mt) acc[g][mt] = f32x4{0.f, 0.f, 0.f, 0.f};

    // L1 sweep: windows kq (h0), kq+8 (h0), kq+16 (h1), kq+24 (h1).
    // A0s/A1s hold the h0 fragments and stay live for the L0 sweep.
    i32x8 A0s[4], A1s[4], A2s[4], A3s[4];
    i32x4 B0s[4], B1s[4];
    ld_A(a0, 16, kq, A0s);       ld_B(p0, kq, B0s);
    ld_A(a0, 16, kq + 8, A1s);   ld_B(p0, kq + 8, B1s);
    ld_A(a1, 16, kq, A2s);       // h1 window kq+16 -> a1 local window kq
    mfma_set(acc, A0s, B0s);
    ld_B(p1, kq, B0s);           // U1 window kq (for A2s)
    ld_A(a1, 16, kq + 8, A3s);   // h1 window kq+24
    mfma_set(acc, A1s, B1s);
    ld_B(p1, kq + 8, B1s);       // U1 window kq+8 (for A3s)
    mfma_set(acc, A2s, B0s);
    mfma_set(acc, A3s, B1s);

    // L0 B prefetch (hides under L1 epilogue): U0 windows kq, kq+8; wave0: x+W0
    i32x4 PB0[4], PB1[4], PBX[4];
    i32x8 PAX[4];
    if (hasL0) {
        ld_B(l0b1, kq, PB0);
        ld_B(l0b1, kq + 8, PB1);
        if (kq == 0) {
            ld_A(l0x, 1, 0, PAX);
            ld_B(l0b0, 0, PBX);
        }
    }

    // L1 epilogue (2 barriers)
    epilogue(acc, b1, c1, h1out, zs, ut, mh, tid, lane, kq);

    // L0 sweep: wave kq computes L0 windows kq+1 (=h0[kq], in A0s) and
    // kq+9 (=h0[kq+8], in A1s); wave 0 additionally window 0 (x, PAX).
    if (hasL0) {
#pragma unroll
        for (int g = 0; g < 4; ++g)
#pragma unroll
            for (int mt = 0; mt < 4; ++mt) acc[g][mt] = f32x4{0.f, 0.f, 0.f, 0.f};

        mfma_set(acc, A0s, PB0);
        mfma_set(acc, A1s, PB1);
        if (kq == 0) mfma_set(acc, PAX, PBX);

        epilogue(acc, b0, c0, h0next, zs, ut, mh, tid, lane, kq);
    }
}

// ---------------- head: y = relu((h1 @ Wd)/1024 + bd); fp8 x fp4 ------------
__global__ __launch_bounds__(256)
void head_mfma(const unsigned char* __restrict__ h1p,
               const unsigned char* __restrict__ Wdp,
               const float* __restrict__ bd, float* __restrict__ y) {
    const int lane = threadIdx.x & 63;
    const int w    = threadIdx.x >> 6;  // k-split wave
    const int ut   = blockIdx.x & 127;
    const int mh   = blockIdx.x >> 7;

    const unsigned char* ap = h1p + ((size_t)(mh * 4) * 16) * 2048 + lane * 32;
    const unsigned char* wp = Wdp + ((size_t)(ut * 16)) * 1024 + lane * 16;

    f32x4 acc[4];
#pragma unroll
    for (int mt = 0; mt < 4; ++mt) acc[mt] = f32x4{0.f, 0.f, 0.f, 0.f};

#pragma unroll
    for (int wi = 0; wi < 4; ++wi) {
        const int W = w + wi * 4;
        i32x4 bq = *reinterpret_cast<const i32x4*>(wp + (size_t)W * 1024);
        i32x8 bf = {bq[0], bq[1], bq[2], bq[3], 0, 0, 0, 0};
#pragma unroll
        for (int mt = 0; mt < 4; ++mt) {
            i32x8 a = *reinterpret_cast<const i32x8*>(ap + (size_t)(mt * 16 + W) * 2048);
            acc[mt] = __builtin_amdgcn_mfma_scale_f32_16x16x128_f8f6f4(
                a, bf, acc[mt], 0, 4, 0, SCL1_, 0, SCL1_);
        }
    }

    __shared__ float zs[4][64][17];
#pragma unroll
    for (int mt = 0; mt < 4; ++mt)
#pragma unroll
        for (int r = 0; r < 4; ++r)
            zs[w][mt * 16 + (lane >> 4) * 4 + r][lane & 15] = acc[mt][r];
    __syncthreads();

    const int tid = threadIdx.x;
    const int lr  = tid >> 2;
    const int u4  = (tid & 3) * 4;
    const int grow = mh * 64 + lr;
    const int gu   = ut * 16 + u4;

    float4 r;
    float* rr = &r.x;
#pragma unroll
    for (int e = 0; e < 4; ++e) {
        float v = (zs[0][lr][u4 + e] + zs[1][lr][u4 + e] +
                   zs[2][lr][u4 + e] + zs[3][lr][u4 + e]) * INV_S_ + bd[gu + e];
        rr[e] = v > 0.f ? v : 0.f;
    }
    *reinterpret_cast<float4*>(&y[(size_t)grow * U_ + gu]) = r;
}

// ---------------- out[b] = sigmoid(y[b,:] @ Wo + bo) ----------------
__global__ __launch_bounds__(256)
void head2(const float* __restrict__ y, const float* __restrict__ Wo,
           const float* __restrict__ bo, float* __restrict__ out) {
    __shared__ float red[256];
    const int b = blockIdx.x;
    const int tid = threadIdx.x;
    float s = 0.f;
    for (int u = tid; u < U_; u += 256) s += y[(size_t)b * U_ + u] * Wo[u];
    red[tid] = s;
    __syncthreads();
    for (int off = 128; off > 0; off >>= 1) {
        if (tid < off) red[tid] += red[tid + off];
        __syncthreads();
    }
    if (tid == 0) out[b] = 1.f / (1.f + __expf(-(red[0] + bo[0])));
}

extern "C" void kernel_launch(void* const* d_in, const int* in_sizes, int n_in,
                              void* d_out, int out_size, void* d_ws, size_t ws_size,
                              hipStream_t stream) {
    const int*   tokens = (const int*)  d_in[0];
    const float* emb    = (const float*)d_in[1];
    const float* W0     = (const float*)d_in[2];
    const float* U0     = (const float*)d_in[3];
    const float* b0     = (const float*)d_in[4];
    const float* W1     = (const float*)d_in[5];
    const float* U1     = (const float*)d_in[6];
    const float* b1     = (const float*)d_in[7];
    const float* Wd     = (const float*)d_in[8];
    const float* bd     = (const float*)d_in[9];
    const float* Wo     = (const float*)d_in[10];
    const float* bo     = (const float*)d_in[11];

    // ws layout (bytes); total ~32 MB
    char* base = (char*)d_ws;
    unsigned char* h0a = (unsigned char*)(base + 0);         // 256 KB (fp8 frag128)
    unsigned char* h1a = (unsigned char*)(base + 262144);    // 256 KB
    float*         c0  = (float*)        (base + 524288);    // 1 MB
    float*         c1  = (float*)        (base + 1572864);   // 1 MB
    unsigned char* h0b = (unsigned char*)(base + 2621440);   // 256 KB
    unsigned char* h1b = (unsigned char*)(base + 2883584);   // 256 KB
    unsigned char* Xp  = (unsigned char*)(base + 3145728);   // 1.25 MB
    float*         yb  = (float*)        (base + 3145728);   // overlays Xp (dead by head)
    unsigned char* W0p = (unsigned char*)(base + 4456448);   // 512 KB (fp4)
    unsigned char* U0p = (unsigned char*)(base + 4980736);   // 8 MB (fp4)
    unsigned char* W1p = (unsigned char*)(base + 13369344);  // 8 MB (fp4)
    unsigned char* U1p = (unsigned char*)(base + 21757952);  // 8 MB (fp4)
    unsigned char* Wdp = (unsigned char*)(base + 30146560);  // 2 MB (fp4)

    // zero h0a, h1a, c0, c1 (contiguous 2.56 MB)
    hipMemsetAsync(d_ws, 0, 2621440, stream);

    embed_pack<<<(T_ * 8 * 64 * 4 + 255) / 256, 256, 0, stream>>>(tokens, emb, Xp);
    pack_all<<<6784, 256, 0, stream>>>(W0, U0, W1, U1, Wd,
                                       W0p, U0p, W1p, U1p, Wdp);

    // prologue: L0(0): x(0) + h0a(=0) -> h0b
    lstm_l0_first<<<256, 512, 0, stream>>>(Xp, W0p, U0p, b0, c0, h0a, h0b);

    // fused phases: phase k = { L1(k), L0(k+1) }
    for (int k = 0; k < T_; ++k) {
        const unsigned char* h0cur  = (k & 1) ? h0a : h0b;
        unsigned char*       h0next = (k & 1) ? h0b : h0a;   // written for k+1
        const unsigned char* h1in   = (k & 1) ? h1b : h1a;
        unsigned char*       h1out  = (k & 1) ? h1a : h1b;
        lstm_phase<<<256, 512, 0, stream>>>(Xp, W0p, U0p, W1p, U1p,
                                            b0, b1, c0, c1,
                                            h0cur, h0next, h1in, h1out, k);
    }
    // h1(79): 79 odd -> h1a
    head_mfma<<<256, 256, 0, stream>>>(h1a, Wdp, bd, yb);
    head2<<<B_, 256, 0, stream>>>(yb, Wo, bo, (float*)d_out);
}

// Round 22
// 904.891 us; speedup vs baseline: 2.5454x; 1.1541x over previous
//
#include <hip/hip_runtime.h>
#include <hip/hip_bf16.h>
#include <hip/hip_fp8.h>
#include <cstdint>

#define B_   128
#define T_   80
#define E_   100
#define U_   2048
#define G4_  8192

// scales: x fp8 x16; h fp4 x128; weights fp4 x64. Unified acc scale 128*64=8192.
// x-window acc (16*64=1024) is multiplied by 8 before h windows accumulate.
#define SA_    16.0f
#define SA4_   128.0f
#define SB4_   64.0f
#define INV_S_ (1.0f / 8192.0f)
#define RXUP_  8.0f
#define SCL1_  0x7F7F7F7F   // E8M0 = 127 -> 2^0 per 32-block (x4 packed)

typedef __attribute__((ext_vector_type(4))) float f32x4;
typedef __attribute__((ext_vector_type(8))) int   i32x8;
typedef __attribute__((ext_vector_type(4))) int   i32x4;

__device__ __forceinline__ unsigned char f2fp8(float x) {
    __hip_fp8_e4m3 q(x);
    return q.__x;
}

// fp4 e2m1 quantize (round to nearest): values {0,.5,1,1.5,2,3,4,6}
__device__ __forceinline__ unsigned int q4(float x) {
    float a = fabsf(x);
    unsigned int s = (x < 0.f) ? 8u : 0u;
    unsigned int c = a < 0.25f ? 0u : a < 0.75f ? 1u : a < 1.25f ? 2u :
                     a < 1.75f ? 3u : a < 2.5f  ? 4u : a < 3.5f  ? 5u :
                     a < 5.0f  ? 6u : 7u;
    return s | c;
}

// pack 2 floats -> fp4 byte (HW convert if available)
__device__ __forceinline__ unsigned char pk4(float v0, float v1) {
#if __has_builtin(__builtin_amdgcn_cvt_scalef32_pk_fp4_f32)
    unsigned int w = __builtin_amdgcn_cvt_scalef32_pk_fp4_f32(0u, v0, v1, 1.0f, 0);
    return (unsigned char)(w & 0xFF);
#else
    return (unsigned char)(q4(v0) | (q4(v1) << 4));
#endif
}

// ---------------- embedding -> fp8 A-frag128 X: 1 window of K=128 -----------
__global__ __launch_bounds__(256)
void embed_pack(const int* __restrict__ tokens, const float* __restrict__ emb,
                unsigned char* __restrict__ Xp) {
    int gtid = blockIdx.x * 256 + threadIdx.x;   // one 8-byte chunk each
    if (gtid >= T_ * 8 * 64 * 4) return;
    int eb   = gtid & 3;
    int lane = (gtid >> 2) & 63;
    int mtg  = (gtid >> 8) & 7;
    int t    = gtid >> 11;
    int row  = (mtg >> 2) * 64 + (mtg & 3) * 16 + (lane & 15);
    const float* erow = emb + (size_t)tokens[row * T_ + t] * E_;
    unsigned char v[8];
#pragma unroll
    for (int j = 0; j < 8; ++j) {
        int k = (lane >> 4) * 32 + eb * 8 + j;
        v[j] = (k < E_) ? f2fp8(SA_ * erow[k]) : 0;
    }
    unsigned char* dst = Xp + ((size_t)(t * 8 + mtg)) * 2048 + lane * 32 + eb * 8;
    *reinterpret_cast<uint2*>(dst) = *reinterpret_cast<const uint2*>(v);
}

// ---------------- fused fp4 pack: coalesced reads, HW convert ---------------
__global__ __launch_bounds__(256)
void pack_all(const float* __restrict__ W0, const float* __restrict__ U0,
              const float* __restrict__ W1, const float* __restrict__ U1,
              const float* __restrict__ Wd,
              unsigned char* __restrict__ W0p, unsigned char* __restrict__ U0p,
              unsigned char* __restrict__ W1p, unsigned char* __restrict__ U1p,
              unsigned char* __restrict__ Wdp) {
    __shared__ float4 st4[32][65];   // [k-row][64 float4 cols + pad]
    const float* stf = reinterpret_cast<const float*>(&st4[0][0]);
    const int tid = threadIdx.x;
    int blk = blockIdx.x;
    const float* W; int K, Ncols, NG, NW; unsigned char* out; int lb;
    if (blk < 2048)      { W = U0; K = U_; Ncols = G4_; NG = 4; NW = 16; out = U0p; lb = blk; }
    else if (blk < 4096) { W = W1; K = U_; Ncols = G4_; NG = 4; NW = 16; out = W1p; lb = blk - 2048; }
    else if (blk < 6144) { W = U1; K = U_; Ncols = G4_; NG = 4; NW = 16; out = U1p; lb = blk - 4096; }
    else if (blk < 6272) { W = W0; K = E_; Ncols = G4_; NG = 4; NW = 1;  out = W0p; lb = blk - 6144; }
    else                 { W = Wd; K = U_; Ncols = U_;  NG = 1; NW = 16; out = Wdp; lb = blk - 6272; }

    int Wm, kg, cg;
    if (NW == 1) { Wm = 0;        kg = lb & 3;         cg = lb >> 2; }
    else         { Wm = lb & 15;  kg = (lb >> 4) & 3;  cg = lb >> 6; }
    int g, utb;
    if (NG == 4) { g = cg >> 3; utb = (cg & 7) * 16; }
    else         { g = 0;       utb = cg * 16; }
    const int cb = cg * 256;     // absolute col base (includes gate offset)

    // stage: reg-stage all 8 rows then write LDS (more loads in flight)
    {
        const int c4 = tid & 63;
        const int r0 = tid >> 6;
        float4 v[8];
#pragma unroll
        for (int p = 0; p < 8; ++p) {
            const int r = p * 4 + r0;
            const int k = Wm * 128 + kg * 32 + r;
            v[p] = make_float4(0.f, 0.f, 0.f, 0.f);
            if (k < K)
                v[p] = *reinterpret_cast<const float4*>(W + (size_t)k * Ncols + cb + c4 * 4);
        }
#pragma unroll
        for (int p = 0; p < 8; ++p) st4[p * 4 + r0][c4] = v[p];
    }
    __syncthreads();

    const int ut_l = tid >> 4;
    const int cl   = tid & 15;
    unsigned char v[16];
#pragma unroll
    for (int b = 0; b < 16; ++b) {
        float v0 = stf[((2 * b)     * 65 + (tid >> 2)) * 4 + (tid & 3)];
        float v1 = stf[((2 * b + 1) * 65 + (tid >> 2)) * 4 + (tid & 3)];
        v[b] = pk4(SB4_ * v0, SB4_ * v1);
    }
    const int ut = utb + ut_l;
    unsigned char* dst = out + (((size_t)(ut * NW + Wm)) * NG + g) * 1024 + (kg * 16 + cl) * 16;
    *reinterpret_cast<uint4*>(dst) = *reinterpret_cast<const uint4*>(v);
}

// ---------------- load / MFMA helpers ---------------------------------------
__device__ __forceinline__ void ld_A(const unsigned char* __restrict__ a,
                                     int stride_nw, int w, i32x8 (&A)[4]) {
#pragma unroll
    for (int mt = 0; mt < 4; ++mt)
        A[mt] = *reinterpret_cast<const i32x8*>(a + (size_t)(mt * stride_nw + w) * 2048);
}

__device__ __forceinline__ void ld_A4(const unsigned char* __restrict__ a,
                                      int stride_nw, int w, i32x4 (&A)[4]) {
#pragma unroll
    for (int mt = 0; mt < 4; ++mt)
        A[mt] = *reinterpret_cast<const i32x4*>(a + (size_t)(mt * stride_nw + w) * 1024);
}

__device__ __forceinline__ void ld_B(const unsigned char* __restrict__ b,
                                     int w, i32x4 (&Bv)[4]) {
#pragma unroll
    for (int g = 0; g < 4; ++g)
        Bv[g] = *reinterpret_cast<const i32x4*>(b + (size_t)(w * 4 + g) * 1024);
}

// A fp8 (cbsz=0), B fp4 (blgp=4) — used for the x window
__device__ __forceinline__ void mfma_set(f32x4 (&acc)[4][4], i32x8 (&A)[4], i32x4 (&Bv)[4]) {
    __builtin_amdgcn_s_setprio(1);
#pragma unroll
    for (int g = 0; g < 4; ++g) {
        i32x8 bf = {Bv[g][0], Bv[g][1], Bv[g][2], Bv[g][3], 0, 0, 0, 0};
#pragma unroll
        for (int mt = 0; mt < 4; ++mt)
            acc[g][mt] = __builtin_amdgcn_mfma_scale_f32_16x16x128_f8f6f4(
                A[mt], bf, acc[g][mt], 0, 4, 0, SCL1_, 0, SCL1_);
    }
    __builtin_amdgcn_s_setprio(0);
}

// A fp4 (cbsz=4), B fp4 (blgp=4) — h windows
__device__ __forceinline__ void mfma_set44(f32x4 (&acc)[4][4], i32x4 (&A)[4], i32x4 (&Bv)[4]) {
    __builtin_amdgcn_s_setprio(1);
#pragma unroll
    for (int g = 0; g < 4; ++g) {
        i32x8 bf = {Bv[g][0], Bv[g][1], Bv[g][2], Bv[g][3], 0, 0, 0, 0};
#pragma unroll
        for (int mt = 0; mt < 4; ++mt) {
            i32x8 af = {A[mt][0], A[mt][1], A[mt][2], A[mt][3], 0, 0, 0, 0};
            acc[g][mt] = __builtin_amdgcn_mfma_scale_f32_16x16x128_f8f6f4(
                af, bf, acc[g][mt], 4, 4, 0, SCL1_, 0, SCL1_);
        }
    }
    __builtin_amdgcn_s_setprio(0);
}

// ---------------- epilogue: single-round reduction + cell update + fp4 h ----
__device__ __forceinline__ void epilogue(
    f32x4 (&acc)[4][4], const float* __restrict__ bias,
    float* __restrict__ c, unsigned char* __restrict__ h_out,
    float (*zs)[4][64][17], int ut, int mh, int tid, int lane, int kq)
{
    const int lr = tid >> 3;          // 0..63
    const int u0 = (tid & 7) * 2;     // 0,2,..,14

    __syncthreads();   // prior zs use complete
#pragma unroll
    for (int g = 0; g < 4; ++g)
#pragma unroll
        for (int mt = 0; mt < 4; ++mt)
#pragma unroll
            for (int r = 0; r < 4; ++r)
                zs[kq][g][mt * 16 + (lane >> 4) * 4 + r][lane & 15] = acc[g][mt][r];
    __syncthreads();

    float zg2[4][2];
#pragma unroll
    for (int g = 0; g < 4; ++g) {
        float s0 = 0.f, s1 = 0.f;
#pragma unroll
        for (int w8 = 0; w8 < 8; ++w8) {
            s0 += zs[w8][g][lr][u0];
            s1 += zs[w8][g][lr][u0 + 1];
        }
        zg2[g][0] = s0;
        zg2[g][1] = s1;
    }

    const int grow = mh * 64 + lr;
    const int unit = ut * 16 + u0;
    const float2 bi  = *reinterpret_cast<const float2*>(&bias[unit]);
    const float2 bfv = *reinterpret_cast<const float2*>(&bias[U_ + unit]);
    const float2 bgv = *reinterpret_cast<const float2*>(&bias[2 * U_ + unit]);
    const float2 bov = *reinterpret_cast<const float2*>(&bias[3 * U_ + unit]);
    float2 cv = *reinterpret_cast<float2*>(&c[(size_t)grow * U_ + unit]);

    float cn[2], hf[2];
#pragma unroll
    for (int e = 0; e < 2; ++e) {
        float zi = zg2[0][e] * INV_S_ + (e ? bi.y : bi.x);
        float zf = zg2[1][e] * INV_S_ + (e ? bfv.y : bfv.x);
        float zg = zg2[2][e] * INV_S_ + (e ? bgv.y : bgv.x);
        float zo = zg2[3][e] * INV_S_ + (e ? bov.y : bov.x);
        float si = 1.f / (1.f + __expf(-zi));
        float sf = 1.f / (1.f + __expf(-zf));
        float so = 1.f / (1.f + __expf(-zo));
        float tg = tanhf(zg);
        float cc = sf * (e ? cv.y : cv.x) + si * tg;
        cn[e] = cc;
        hf[e] = so * tanhf(cc);
    }
    *reinterpret_cast<float2*>(&c[(size_t)grow * U_ + unit]) = make_float2(cn[0], cn[1]);

    // fp4 h write in A-frag128 fp4 layout (16 windows, 1024 B each)
    const int mt  = lr >> 4;
    const int cl  = lr & 15;
    const int Wh  = unit >> 7;
    const int lgg = (unit >> 5) & 3;
    size_t fr = (size_t)(mh * 4 + mt) * 16 + Wh;
    h_out[fr * 1024 + (lgg * 16 + cl) * 16 + ((unit & 31) >> 1)] =
        pk4(SA4_ * hf[0], SA4_ * hf[1]);
}

// ---------------- prologue: L0(0) = x(0) @ W0 only (h(-1)=0) ----------------
__global__ __launch_bounds__(512)
void lstm_l0_first(const unsigned char* __restrict__ Xp,
                   const unsigned char* __restrict__ W0p,
                   const float* __restrict__ b0,
                   float* __restrict__ c0,
                   unsigned char* __restrict__ h0out) {
    __shared__ float zs[8][4][64][17];
    const int tid  = threadIdx.x;
    const int lane = tid & 63;
    const int kq   = tid >> 6;
    const int b    = blockIdx.x;
    const int s    = b >> 3;
    const int ut   = (b & 7) * 16 + (s >> 1);
    const int mh   = s & 1;

    f32x4 acc[4][4];
#pragma unroll
    for (int g = 0; g < 4; ++g)
#pragma unroll
        for (int mt = 0; mt < 4; ++mt) acc[g][mt] = f32x4{0.f, 0.f, 0.f, 0.f};

    if (kq == 0) {
        const unsigned char* l0x  = Xp + ((size_t)(mh * 4) * 1) * 2048 + lane * 32;
        const unsigned char* l0b0 = W0p + ((size_t)(ut * 1) * 4) * 1024 + lane * 16;
        i32x8 PAX[4];
        i32x4 PBX[4];
        ld_A(l0x, 1, 0, PAX);
        ld_B(l0b0, 0, PBX);
        mfma_set(acc, PAX, PBX);
#pragma unroll
        for (int g = 0; g < 4; ++g)
#pragma unroll
            for (int mt = 0; mt < 4; ++mt)
#pragma unroll
                for (int r = 0; r < 4; ++r) acc[g][mt][r] *= RXUP_;
    }

    epilogue(acc, b0, c0, h0out, zs, ut, mh, tid, lane, kq);
}

// ---------------- fused phase k: L1(k) sweep, L0(k+1) reusing h0 regs -------
__global__ __launch_bounds__(512)
void lstm_phase(const unsigned char* __restrict__ Xp,
                const unsigned char* __restrict__ W0p,
                const unsigned char* __restrict__ U0p,
                const unsigned char* __restrict__ W1p,
                const unsigned char* __restrict__ U1p,
                const float* __restrict__ b0,
                const float* __restrict__ b1,
                float* __restrict__ c0, float* __restrict__ c1,
                const unsigned char* __restrict__ h0cur,
                unsigned char* __restrict__ h0next,
                const unsigned char* __restrict__ h1in,
                unsigned char* __restrict__ h1out,
                int k) {
    __shared__ float zs[8][4][64][17];
    const int tid  = threadIdx.x;
    const int lane = tid & 63;
    const int kq   = tid >> 6;
    const int b    = blockIdx.x;
    const int s    = b >> 3;
    const int ut   = (b & 7) * 16 + (s >> 1);   // xcd owns 16 consecutive ut
    const int mh   = s & 1;
    const bool hasL0 = (k + 1 < T_);

    // L1 operand pointers; h panels fp4 (1024 B windows)
    const unsigned char* a0 = h0cur + ((size_t)(mh * 4) * 16) * 1024 + lane * 16;
    const unsigned char* a1 = h1in  + ((size_t)(mh * 4) * 16) * 1024 + lane * 16;
    const unsigned char* p0 = W1p + ((size_t)(ut * 16) * 4) * 1024 + lane * 16;
    const unsigned char* p1 = U1p + ((size_t)(ut * 16) * 4) * 1024 + lane * 16;
    // L0 operand pointers (x fp8, 2048 B window)
    const unsigned char* l0x  = Xp + (size_t)(k + 1) * 8 * 2048
                                   + ((size_t)(mh * 4) * 1) * 2048 + lane * 32;
    const unsigned char* l0b0 = W0p + ((size_t)(ut * 1)  * 4) * 1024 + lane * 16;
    const unsigned char* l0b1 = U0p + ((size_t)(ut * 16) * 4) * 1024 + lane * 16;

    f32x4 acc[4][4];
#pragma unroll
    for (int g = 0; g < 4; ++g)
#pragma unroll
        for (int mt = 0; mt < 4; ++mt) acc[g][mt] = f32x4{0.f, 0.f, 0.f, 0.f};

    // L1 sweep: windows kq (h0), kq+8 (h0), kq+16 (h1), kq+24 (h1).
    // A0s/A1s hold the h0 fragments and stay live for the L0 sweep.
    i32x4 A0s[4], A1s[4], A2s[4], A3s[4];
    i32x4 B0s[4], B1s[4];
    ld_A4(a0, 16, kq, A0s);       ld_B(p0, kq, B0s);
    ld_A4(a0, 16, kq + 8, A1s);   ld_B(p0, kq + 8, B1s);
    ld_A4(a1, 16, kq, A2s);       // h1 window kq+16 -> a1 local window kq
    mfma_set44(acc, A0s, B0s);
    ld_B(p1, kq, B0s);            // U1 window kq (for A2s)
    ld_A4(a1, 16, kq + 8, A3s);   // h1 window kq+24
    mfma_set44(acc, A1s, B1s);
    ld_B(p1, kq + 8, B1s);        // U1 window kq+8 (for A3s)
    mfma_set44(acc, A2s, B0s);
    mfma_set44(acc, A3s, B1s);

    // L0 B prefetch (hides under L1 epilogue): U0 windows kq, kq+8; wave0: x+W0
    i32x4 PB0[4], PB1[4], PBX[4];
    i32x8 PAX[4];
    if (hasL0) {
        ld_B(l0b1, kq, PB0);
        ld_B(l0b1, kq + 8, PB1);
        if (kq == 0) {
            ld_A(l0x, 1, 0, PAX);
            ld_B(l0b0, 0, PBX);
        }
    }

    // L1 epilogue (2 barriers)
    epilogue(acc, b1, c1, h1out, zs, ut, mh, tid, lane, kq);

    // L0 sweep: x window first (wave 0, fp8 scale -> x8), then h windows:
    // wave kq computes L0 windows kq+1 (=h0[kq], A0s) and kq+9 (=h0[kq+8], A1s).
    if (hasL0) {
#pragma unroll
        for (int g = 0; g < 4; ++g)
#pragma unroll
            for (int mt = 0; mt < 4; ++mt) acc[g][mt] = f32x4{0.f, 0.f, 0.f, 0.f};

        if (kq == 0) {
            mfma_set(acc, PAX, PBX);
#pragma unroll
            for (int g = 0; g < 4; ++g)
#pragma unroll
                for (int mt = 0; mt < 4; ++mt)
#pragma unroll
                    for (int r = 0; r < 4; ++r) acc[g][mt][r] *= RXUP_;
        }
        mfma_set44(acc, A0s, PB0);
        mfma_set44(acc, A1s, PB1);

        epilogue(acc, b0, c0, h0next, zs, ut, mh, tid, lane, kq);
    }
}

// ---------------- head: y = relu((h1 @ Wd)/8192 + bd); fp4 x fp4 ------------
__global__ __launch_bounds__(256)
void head_mfma(const unsigned char* __restrict__ h1p,
               const unsigned char* __restrict__ Wdp,
               const float* __restrict__ bd, float* __restrict__ y) {
    const int lane = threadIdx.x & 63;
    const int w    = threadIdx.x >> 6;  // k-split wave
    const int ut   = blockIdx.x & 127;
    const int mh   = blockIdx.x >> 7;

    const unsigned char* ap = h1p + ((size_t)(mh * 4) * 16) * 1024 + lane * 16;
    const unsigned char* wp = Wdp + ((size_t)(ut * 16)) * 1024 + lane * 16;

    f32x4 acc[4];
#pragma unroll
    for (int mt = 0; mt < 4; ++mt) acc[mt] = f32x4{0.f, 0.f, 0.f, 0.f};

#pragma unroll
    for (int wi = 0; wi < 4; ++wi) {
        const int W = w + wi * 4;
        i32x4 bq = *reinterpret_cast<const i32x4*>(wp + (size_t)W * 1024);
        i32x8 bf = {bq[0], bq[1], bq[2], bq[3], 0, 0, 0, 0};
#pragma unroll
        for (int mt = 0; mt < 4; ++mt) {
            i32x4 aq = *reinterpret_cast<const i32x4*>(ap + (size_t)(mt * 16 + W) * 1024);
            i32x8 af = {aq[0], aq[1], aq[2], aq[3], 0, 0, 0, 0};
            acc[mt] = __builtin_amdgcn_mfma_scale_f32_16x16x128_f8f6f4(
                af, bf, acc[mt], 4, 4, 0, SCL1_, 0, SCL1_);
        }
    }

    __shared__ float zs[4][64][17];
#pragma unroll
    for (int mt = 0; mt < 4; ++mt)
#pragma unroll
        for (int r = 0; r < 4; ++r)
            zs[w][mt * 16 + (lane >> 4) * 4 + r][lane & 15] = acc[mt][r];
    __syncthreads();

    const int tid = threadIdx.x;
    const int lr  = tid >> 2;
    const int u4  = (tid & 3) * 4;
    const int grow = mh * 64 + lr;
    const int gu   = ut * 16 + u4;

    float4 r;
    float* rr = &r.x;
#pragma unroll
    for (int e = 0; e < 4; ++e) {
        float v = (zs[0][lr][u4 + e] + zs[1][lr][u4 + e] +
                   zs[2][lr][u4 + e] + zs[3][lr][u4 + e]) * INV_S_ + bd[gu + e];
        rr[e] = v > 0.f ? v : 0.f;
    }
    *reinterpret_cast<float4*>(&y[(size_t)grow * U_ + gu]) = r;
}

// ---------------- out[b] = sigmoid(y[b,:] @ Wo + bo) ----------------
__global__ __launch_bounds__(256)
void head2(const float* __restrict__ y, const float* __restrict__ Wo,
           const float* __restrict__ bo, float* __restrict__ out) {
    __shared__ float red[256];
    const int b = blockIdx.x;
    const int tid = threadIdx.x;
    float s = 0.f;
    for (int u = tid; u < U_; u += 256) s += y[(size_t)b * U_ + u] * Wo[u];
    red[tid] = s;
    __syncthreads();
    for (int off = 128; off > 0; off >>= 1) {
        if (tid < off) red[tid] += red[tid + off];
        __syncthreads();
    }
    if (tid == 0) out[b] = 1.f / (1.f + __expf(-(red[0] + bo[0])));
}

extern "C" void kernel_launch(void* const* d_in, const int* in_sizes, int n_in,
                              void* d_out, int out_size, void* d_ws, size_t ws_size,
                              hipStream_t stream) {
    const int*   tokens = (const int*)  d_in[0];
    const float* emb    = (const float*)d_in[1];
    const float* W0     = (const float*)d_in[2];
    const float* U0     = (const float*)d_in[3];
    const float* b0     = (const float*)d_in[4];
    const float* W1     = (const float*)d_in[5];
    const float* U1     = (const float*)d_in[6];
    const float* b1     = (const float*)d_in[7];
    const float* Wd     = (const float*)d_in[8];
    const float* bd     = (const float*)d_in[9];
    const float* Wo     = (const float*)d_in[10];
    const float* bo     = (const float*)d_in[11];

    // ws layout (bytes); total ~32 MB
    char* base = (char*)d_ws;
    unsigned char* h0a = (unsigned char*)(base + 0);         // 128 KB (fp4 frag128)
    unsigned char* h1a = (unsigned char*)(base + 262144);    // 128 KB
    float*         c0  = (float*)        (base + 524288);    // 1 MB
    float*         c1  = (float*)        (base + 1572864);   // 1 MB
    unsigned char* h0b = (unsigned char*)(base + 2621440);   // 128 KB
    unsigned char* h1b = (unsigned char*)(base + 2883584);   // 128 KB
    unsigned char* Xp  = (unsigned char*)(base + 3145728);   // 1.25 MB
    float*         yb  = (float*)        (base + 3145728);   // overlays Xp (dead by head)
    unsigned char* W0p = (unsigned char*)(base + 4456448);   // 512 KB (fp4)
    unsigned char* U0p = (unsigned char*)(base + 4980736);   // 8 MB (fp4)
    unsigned char* W1p = (unsigned char*)(base + 13369344);  // 8 MB (fp4)
    unsigned char* U1p = (unsigned char*)(base + 21757952);  // 8 MB (fp4)
    unsigned char* Wdp = (unsigned char*)(base + 30146560);  // 2 MB (fp4)

    // zero h0a, h1a, c0, c1 (contiguous 2.56 MB)
    hipMemsetAsync(d_ws, 0, 2621440, stream);

    embed_pack<<<(T_ * 8 * 64 * 4 + 255) / 256, 256, 0, stream>>>(tokens, emb, Xp);
    pack_all<<<6784, 256, 0, stream>>>(W0, U0, W1, U1, Wd,
                                       W0p, U0p, W1p, U1p, Wdp);

    // prologue: L0(0): x(0) @ W0 -> h0b (h(-1) = 0)
    lstm_l0_first<<<256, 512, 0, stream>>>(Xp, W0p, b0, c0, h0b);

    // fused phases: phase k = { L1(k), L0(k+1) }
    for (int k = 0; k < T_; ++k) {
        const unsigned char* h0cur  = (k & 1) ? h0a : h0b;
        unsigned char*       h0next = (k & 1) ? h0b : h0a;   // written for k+1
        const unsigned char* h1in   = (k & 1) ? h1b : h1a;
        unsigned char*       h1out  = (k & 1) ? h1a : h1b;
        lstm_phase<<<256, 512, 0, stream>>>(Xp, W0p, U0p, W1p, U1p,
                                            b0, b1, c0, c1,
                                            h0cur, h0next, h1in, h1out, k);
    }
    // h1(79): 79 odd -> h1a
    head_mfma<<<256, 256, 0, stream>>>(h1a, Wdp, bd, yb);
    head2<<<B_, 256, 0, stream>>>(yb, Wo, bo, (float*)d_out);
}